// Round 1
// baseline (438.975 us; speedup 1.0000x reference)
//
#include <hip/hip_runtime.h>
#include <hip/hip_bf16.h>

typedef short short8 __attribute__((ext_vector_type(8)));
typedef float f32x4  __attribute__((ext_vector_type(4)));

#define B_ 2
#define C_ 512
#define N_ 4096
#define G_ 32

static __device__ __forceinline__ short f2bf(float f) {
    return __builtin_bit_cast(short, __float2bfloat16(f));
}

// ---- fp32 -> bf16 weight convert ----
__global__ void cvt_bf16(const float* __restrict__ src, short* __restrict__ dst, int n) {
    int i = blockIdx.x * 256 + threadIdx.x;
    if (i < n) dst[i] = f2bf(src[i]);
}

// ---- groupnorm stats: one block per (b,g); 16 channels * 4096 contiguous floats ----
__global__ void gn_stats(const float* __restrict__ x, float* __restrict__ stats) {
    const float4* p = (const float4*)(x + (size_t)blockIdx.x * 16 * N_);
    int tid = threadIdx.x;
    float s = 0.f, sq = 0.f;
    for (int i = tid; i < (16 * N_) / 4; i += 256) {
        float4 t = p[i];
        s  += t.x + t.y + t.z + t.w;
        sq += t.x*t.x + t.y*t.y + t.z*t.z + t.w*t.w;
    }
    __shared__ float rs[256], rq[256];
    rs[tid] = s; rq[tid] = sq;
    __syncthreads();
    for (int h = 128; h > 0; h >>= 1) {
        if (tid < h) { rs[tid] += rs[tid+h]; rq[tid] += rq[tid+h]; }
        __syncthreads();
    }
    if (tid == 0) {
        float mean = rs[0] / (16.f * N_);
        float var  = rq[0] / (16.f * N_) - mean * mean;
        stats[blockIdx.x*2+0] = mean;
        stats[blockIdx.x*2+1] = rsqrtf(var + 1e-6f);
    }
}

// ---- groupnorm apply + transpose: x[b,c,n] fp32 -> Hn[b,n,c] bf16 ----
__global__ void gn_apply(const float* __restrict__ x, const float* __restrict__ stats,
                         const float* __restrict__ gw, const float* __restrict__ gb,
                         short* __restrict__ hn) {
    __shared__ short t[64 * 68];
    const int n0 = blockIdx.x * 64, c0 = blockIdx.y * 64, b = blockIdx.z;
    const int lane = threadIdx.x & 63, w = threadIdx.x >> 6;
    #pragma unroll
    for (int rep = 0; rep < 16; rep++) {
        int c  = rep * 4 + w;            // 0..63
        int cc = c0 + c;
        int g  = cc >> 4;
        float mean = stats[(b*G_ + g)*2 + 0];
        float rstd = stats[(b*G_ + g)*2 + 1];
        float sc = gw[cc] * rstd;
        float bi = gb[cc] - mean * sc;
        float v = x[((size_t)(b*C_ + cc)) * N_ + n0 + lane];
        t[lane*68 + c] = f2bf(v * sc + bi);
    }
    __syncthreads();
    #pragma unroll
    for (int rep = 0; rep < 16; rep++) {
        int n = rep * 4 + w;
        hn[((size_t)(b*N_ + n0 + n)) * C_ + c0 + lane] = t[n*68 + lane];
    }
}

// ---- generic NT GEMM: C[m,n] = alpha * sum_k A[m,k]*B[n,k] (+bias) (+residual) ----
// BIAS_MODE: 0 none, 1 per-col, 2 per-row. OUT_MODE: 0 bf16, 1 fp32, 2 fp32 + residual.
// 128x128 tile, BK=32, 4 waves (2x2), each wave 64x64 via 4x4 mfma_f32_16x16x32_bf16.
template<int BIAS_MODE, int OUT_MODE>
__global__ __launch_bounds__(256, 2)
void gemm_nt(const short* __restrict__ A, int lda, long long sAz,
             const short* __restrict__ Bm, int ldb, long long sBz,
             void* __restrict__ Cv, int ldc, long long sCz,
             const float* __restrict__ bias,
             const float* __restrict__ res,
             float alpha, int K) {
    __shared__ short As[128 * 40];
    __shared__ short Bs[128 * 40];
    const int tid  = threadIdx.x;
    const int lane = tid & 63;
    const int wid  = tid >> 6;
    const int wr   = wid >> 1;          // 0..1
    const int wc   = wid & 1;           // 0..1
    const int m0 = blockIdx.y * 128;
    const int n0 = blockIdx.x * 128;
    const int z  = blockIdx.z;

    const int sr = tid >> 2;            // 0..63
    const int sc = (tid & 3) << 3;      // 0,8,16,24

    const short* Ap = A  + sAz * z + (long long)(m0 + sr) * lda + sc;
    const short* Bp = Bm + sBz * z + (long long)(n0 + sr) * ldb + sc;

    f32x4 acc[4][4];
    #pragma unroll
    for (int i = 0; i < 4; i++)
        #pragma unroll
        for (int j = 0; j < 4; j++)
            acc[i][j] = f32x4{0.f, 0.f, 0.f, 0.f};

    const int fm = lane & 15;
    const int fq = (lane >> 4) << 3;    // 0,8,16,24

    for (int k0 = 0; k0 < K; k0 += 32) {
        short8 a0 = *(const short8*)(Ap + k0);
        short8 a1 = *(const short8*)(Ap + (long long)64 * lda + k0);
        short8 b0 = *(const short8*)(Bp + k0);
        short8 b1 = *(const short8*)(Bp + (long long)64 * ldb + k0);
        __syncthreads();
        *(short8*)&As[sr*40 + sc]        = a0;
        *(short8*)&As[(sr+64)*40 + sc]   = a1;
        *(short8*)&Bs[sr*40 + sc]        = b0;
        *(short8*)&Bs[(sr+64)*40 + sc]   = b1;
        __syncthreads();
        short8 af[4], bf[4];
        #pragma unroll
        for (int i = 0; i < 4; i++) af[i] = *(const short8*)&As[(wr*64 + i*16 + fm)*40 + fq];
        #pragma unroll
        for (int i = 0; i < 4; i++) bf[i] = *(const short8*)&Bs[(wc*64 + i*16 + fm)*40 + fq];
        #pragma unroll
        for (int mi = 0; mi < 4; mi++)
            #pragma unroll
            for (int ni = 0; ni < 4; ni++)
                acc[mi][ni] = __builtin_amdgcn_mfma_f32_16x16x32_bf16(af[mi], bf[ni], acc[mi][ni], 0, 0, 0);
    }

    const int colb = n0 + wc*64 + fm;
    const int rowb = m0 + wr*64 + ((lane >> 4) << 2);
    #pragma unroll
    for (int mi = 0; mi < 4; mi++) {
        #pragma unroll
        for (int ni = 0; ni < 4; ni++) {
            int cc = colb + ni*16;
            float cb = (BIAS_MODE == 1) ? bias[cc] : 0.f;
            #pragma unroll
            for (int r = 0; r < 4; r++) {
                int rr = rowb + mi*16 + r;
                float val = acc[mi][ni][r] * alpha + cb;
                if (BIAS_MODE == 2) val += bias[rr];
                long long idx = sCz * z + (long long)rr * ldc + cc;
                if (OUT_MODE == 0)      ((short*)Cv)[idx] = f2bf(val);
                else if (OUT_MODE == 1) ((float*)Cv)[idx] = val;
                else                    ((float*)Cv)[idx] = val + res[idx];
            }
        }
    }
}

// ---- row softmax over 4096 fp32, writes bf16 in place at row head ----
__global__ void softmax_rows(float* __restrict__ S) {
    const int tid = threadIdx.x;
    float* row = S + (size_t)blockIdx.x * N_;
    const float4* rv = (const float4*)row;
    float4 v[4];
    float mx = -3.0e38f;
    #pragma unroll
    for (int i = 0; i < 4; i++) {
        v[i] = rv[tid*4 + i];
        mx = fmaxf(mx, fmaxf(fmaxf(v[i].x, v[i].y), fmaxf(v[i].z, v[i].w)));
    }
    __shared__ float red[256];
    red[tid] = mx; __syncthreads();
    for (int h = 128; h > 0; h >>= 1) { if (tid < h) red[tid] = fmaxf(red[tid], red[tid+h]); __syncthreads(); }
    mx = red[0]; __syncthreads();
    float f[16]; float sum = 0.f;
    #pragma unroll
    for (int i = 0; i < 4; i++) {
        f[i*4+0] = __expf(v[i].x - mx);
        f[i*4+1] = __expf(v[i].y - mx);
        f[i*4+2] = __expf(v[i].z - mx);
        f[i*4+3] = __expf(v[i].w - mx);
        sum += f[i*4+0] + f[i*4+1] + f[i*4+2] + f[i*4+3];
    }
    red[tid] = sum; __syncthreads();
    for (int h = 128; h > 0; h >>= 1) { if (tid < h) red[tid] += red[tid+h]; __syncthreads(); }
    float inv = 1.f / red[0];
    short* ob = (short*)row;
    short8 o0, o1;
    #pragma unroll
    for (int j = 0; j < 8; j++) o0[j] = f2bf(f[j] * inv);
    #pragma unroll
    for (int j = 0; j < 8; j++) o1[j] = f2bf(f[8+j] * inv);
    *(short8*)&ob[tid*16]     = o0;
    *(short8*)&ob[tid*16 + 8] = o1;
}

extern "C" void kernel_launch(void* const* d_in, const int* in_sizes, int n_in,
                              void* d_out, int out_size, void* d_ws, size_t ws_size,
                              hipStream_t stream) {
    const float* x   = (const float*)d_in[0];
    const float* gnw = (const float*)d_in[1];
    const float* gnb = (const float*)d_in[2];
    const float* wq  = (const float*)d_in[3];
    const float* bq  = (const float*)d_in[4];
    const float* wk  = (const float*)d_in[5];
    const float* bk  = (const float*)d_in[6];
    const float* wv  = (const float*)d_in[7];
    const float* bv  = (const float*)d_in[8];
    const float* wp  = (const float*)d_in[9];
    const float* bp  = (const float*)d_in[10];
    float* out = (float*)d_out;
    char*  ws  = (char*)d_ws;

    // workspace layout (~108 MB total)
    float* stats = (float*)(ws + 0);                 // 512 B
    short* Wb    = (short*)(ws + 4096);              // 2 MB  [4][512][512] bf16
    short* Hn    = (short*)(ws + (4ull  << 20));     // 8 MB  [2][4096][512] bf16
    short* Qt    = (short*)(ws + (12ull << 20));     // 8 MB  [2][4096][512]
    short* Kt    = (short*)(ws + (20ull << 20));     // 8 MB  [2][4096][512]
    short* Vc    = (short*)(ws + (28ull << 20));     // 8 MB  [2][512][4096]
    short* Ot    = (short*)(ws + (36ull << 20));     // 8 MB  [2][4096][512]
    float* Sb    = (float*)(ws + (44ull << 20));     // 64 MB [4096][4096] fp32 (reused per batch)

    const int WN = C_ * C_;                          // 262144
    cvt_bf16<<<WN/256, 256, 0, stream>>>(wq, Wb + 0*WN, WN);
    cvt_bf16<<<WN/256, 256, 0, stream>>>(wk, Wb + 1*WN, WN);
    cvt_bf16<<<WN/256, 256, 0, stream>>>(wv, Wb + 2*WN, WN);
    cvt_bf16<<<WN/256, 256, 0, stream>>>(wp, Wb + 3*WN, WN);

    gn_stats<<<B_*G_, 256, 0, stream>>>(x, stats);
    gn_apply<<<dim3(N_/64, C_/64, B_), 256, 0, stream>>>(x, stats, gnw, gnb, Hn);

    const long long sBN = (long long)N_ * C_;        // per-batch plane, elements

    // Q,K: [4096,512] = Hn @ W^T + b (bias per col = out channel)
    gemm_nt<1,0><<<dim3(4, 32, 2), 256, 0, stream>>>(Hn, C_, sBN, Wb + 0*WN, C_, 0, Qt, C_, sBN, bq, nullptr, 1.f, C_);
    gemm_nt<1,0><<<dim3(4, 32, 2), 256, 0, stream>>>(Hn, C_, sBN, Wb + 1*WN, C_, 0, Kt, C_, sBN, bk, nullptr, 1.f, C_);
    // V: [512,4096] = Wv @ Hn^T + bv (bias per row = out channel)
    gemm_nt<2,0><<<dim3(32, 4, 2), 256, 0, stream>>>(Wb + 2*WN, C_, 0, Hn, C_, sBN, Vc, N_, sBN, bv, nullptr, 1.f, C_);

    const float scale = 0.044194173824159216f;       // 512^-0.5
    for (int b = 0; b < 2; ++b) {
        // S = Qt @ Kt^T * scale  (fp32, [4096,4096])
        gemm_nt<0,1><<<dim3(32, 32, 1), 256, 0, stream>>>(Qt + b*sBN, C_, 0, Kt + b*sBN, C_, 0, Sb, N_, 0, nullptr, nullptr, scale, C_);
        // softmax rows, bf16 in place (row stride stays 8192 bf16 elems)
        softmax_rows<<<N_, 256, 0, stream>>>(Sb);
        // Ot = P @ Vc^T : [4096,512]
        gemm_nt<0,0><<<dim3(4, 32, 1), 256, 0, stream>>>((const short*)Sb, 2*N_, 0, Vc + b*sBN, N_, 0, Ot + b*sBN, C_, 0, nullptr, nullptr, 1.f, N_);
    }

    // out[b,o,n] = x + Wp @ Ot^T + bp  (fp32, coalesced along n)
    gemm_nt<2,2><<<dim3(32, 4, 2), 256, 0, stream>>>(Wb + 3*WN, C_, 0, Ot, C_, sBN, out, N_, sBN, bp, x, 1.f, C_);
}

// Round 2
// 395.549 us; speedup vs baseline: 1.1098x; 1.1098x over previous
//
#include <hip/hip_runtime.h>
#include <hip/hip_bf16.h>
#include <stdint.h>

typedef short short8 __attribute__((ext_vector_type(8)));
typedef float f32x4  __attribute__((ext_vector_type(4)));

#define B_ 2
#define C_ 512
#define N_ 4096
#define G_ 32

static __device__ __forceinline__ short f2bf(float f) {
    return __builtin_bit_cast(short, __float2bfloat16(f));
}

// async global->LDS DMA, 16 bytes per lane. LDS dest = wave-uniform base + lane*16.
static __device__ __forceinline__ void async16(short* lds_wave_base, const short* g) {
    auto l  = (__attribute__((address_space(3))) unsigned int*)(uintptr_t)(lds_wave_base);
    auto gg = (const __attribute__((address_space(1))) unsigned int*)(g);
    __builtin_amdgcn_global_load_lds(gg, l, 16, 0, 0);
}

// ---- fp32 -> bf16 weight convert ----
__global__ void cvt_bf16(const float* __restrict__ src, short* __restrict__ dst, int n) {
    int i = blockIdx.x * 256 + threadIdx.x;
    if (i < n) dst[i] = f2bf(src[i]);
}

// ---- groupnorm stats: one block per (b,g); 16 channels * 4096 contiguous floats ----
__global__ void gn_stats(const float* __restrict__ x, float* __restrict__ stats) {
    const float4* p = (const float4*)(x + (size_t)blockIdx.x * 16 * N_);
    int tid = threadIdx.x;
    float s = 0.f, sq = 0.f;
    for (int i = tid; i < (16 * N_) / 4; i += 256) {
        float4 t = p[i];
        s  += t.x + t.y + t.z + t.w;
        sq += t.x*t.x + t.y*t.y + t.z*t.z + t.w*t.w;
    }
    __shared__ float rs[256], rq[256];
    rs[tid] = s; rq[tid] = sq;
    __syncthreads();
    for (int h = 128; h > 0; h >>= 1) {
        if (tid < h) { rs[tid] += rs[tid+h]; rq[tid] += rq[tid+h]; }
        __syncthreads();
    }
    if (tid == 0) {
        float mean = rs[0] / (16.f * N_);
        float var  = rq[0] / (16.f * N_) - mean * mean;
        stats[blockIdx.x*2+0] = mean;
        stats[blockIdx.x*2+1] = rsqrtf(var + 1e-6f);
    }
}

// ---- groupnorm apply + transpose: x[b,c,n] fp32 -> Hn[b,n,c] bf16 ----
__global__ void gn_apply(const float* __restrict__ x, const float* __restrict__ stats,
                         const float* __restrict__ gw, const float* __restrict__ gb,
                         short* __restrict__ hn) {
    __shared__ short t[64 * 68];
    const int n0 = blockIdx.x * 64, c0 = blockIdx.y * 64, b = blockIdx.z;
    const int lane = threadIdx.x & 63, w = threadIdx.x >> 6;
    #pragma unroll
    for (int rep = 0; rep < 16; rep++) {
        int c  = rep * 4 + w;            // 0..63
        int cc = c0 + c;
        int g  = cc >> 4;
        float mean = stats[(b*G_ + g)*2 + 0];
        float rstd = stats[(b*G_ + g)*2 + 1];
        float sc = gw[cc] * rstd;
        float bi = gb[cc] - mean * sc;
        float v = x[((size_t)(b*C_ + cc)) * N_ + n0 + lane];
        t[lane*68 + c] = f2bf(v * sc + bi);
    }
    __syncthreads();
    #pragma unroll
    for (int rep = 0; rep < 16; rep++) {
        int n = rep * 4 + w;
        hn[((size_t)(b*N_ + n0 + n)) * C_ + c0 + lane] = t[n*68 + lane];
    }
}

// ---- generic NT GEMM: C[m,n] = alpha * sum_k A[m,k]*B[n,k] (+bias) (+residual) ----
// m97-style: global_load_lds width-16 staging, single LDS buffer, 2 barriers/iter.
// XOR-swizzled LDS chunk placement (slot cs holds global chunk cs^((r>>1)&3)) makes
// ds_read_b128 fragment reads exactly 2-way banked (free).
// BIAS_MODE: 0 none, 1 per-col, 2 per-row. OUT_MODE: 0 bf16, 1 fp32, 2 fp32 + residual.
// BM in {128, 64}; BN=128, BK=32. 4 waves (2x2), wave tile (BM/2) x 64.
template<int BM, int BIAS_MODE, int OUT_MODE>
__global__ __launch_bounds__(256, 2)
void gemm_nt(const short* __restrict__ A, int lda, long long sAz,
             const short* __restrict__ Bm, int ldb, long long sBz,
             void* __restrict__ Cv, int ldc, long long sCz,
             const float* __restrict__ bias,
             const float* __restrict__ res,
             float alpha, int K) {
    constexpr int MI = BM / 32;              // 4 for BM=128, 2 for BM=64
    __shared__ short As[BM * 32];
    __shared__ short Bs[128 * 32];
    const int tid  = threadIdx.x;
    const int lane = tid & 63;
    const int wid  = tid >> 6;
    const int wr   = wid >> 1;               // 0..1
    const int wc   = wid & 1;                // 0..1
    const int m0 = blockIdx.y * BM;
    const int n0 = blockIdx.x * 128;
    const int z  = blockIdx.z;

    // staging assignment: thread t -> row r = t>>2, LDS chunk slot cs = t&3,
    // fetches global chunk gc = cs ^ ((r>>1)&3)  (each chunk = 16 B = 8 shorts)
    const int r  = tid >> 2;                 // 0..63
    const int gc = (tid & 3) ^ ((r >> 1) & 3);

    const short* Ap  = A  + sAz * z + (long long)(m0 + r) * lda + gc * 8;
    const short* Bp  = Bm + sBz * z + (long long)(n0 + r) * ldb + gc * 8;
    const short* Ap1 = Ap + (long long)64 * lda;
    const short* Bp1 = Bp + (long long)64 * ldb;

    short* AsW = As + wid * 512;             // per-wave LDS base (1024 B per wave-issue)
    short* BsW = Bs + wid * 512;

    f32x4 acc[MI][4];
    #pragma unroll
    for (int i = 0; i < MI; i++)
        #pragma unroll
        for (int j = 0; j < 4; j++)
            acc[i][j] = f32x4{0.f, 0.f, 0.f, 0.f};

    const int fm  = lane & 15;
    const int q   = lane >> 4;               // k-chunk index 0..3
    const int swz = ((q ^ ((fm >> 1) & 3)) << 3);  // un-swizzled short offset in row

    for (int k0 = 0; k0 < K; k0 += 32) {
        __syncthreads();                     // LDS from prev iter fully consumed
        async16(AsW,        Ap  + k0);
        if (BM == 128) async16(AsW + 2048, Ap1 + k0);
        async16(BsW,        Bp  + k0);
        async16(BsW + 2048, Bp1 + k0);
        __syncthreads();                     // compiler drains vmcnt before barrier
        short8 af[MI], bf[4];
        #pragma unroll
        for (int i = 0; i < MI; i++)
            af[i] = *(const short8*)&As[(wr*(BM/2) + i*16 + fm)*32 + swz];
        #pragma unroll
        for (int i = 0; i < 4; i++)
            bf[i] = *(const short8*)&Bs[(wc*64 + i*16 + fm)*32 + swz];
        #pragma unroll
        for (int mi = 0; mi < MI; mi++)
            #pragma unroll
            for (int ni = 0; ni < 4; ni++)
                acc[mi][ni] = __builtin_amdgcn_mfma_f32_16x16x32_bf16(af[mi], bf[ni], acc[mi][ni], 0, 0, 0);
    }

    const int colb = n0 + wc*64 + fm;
    const int rowb = m0 + wr*(BM/2) + (q << 2);
    #pragma unroll
    for (int mi = 0; mi < MI; mi++) {
        #pragma unroll
        for (int ni = 0; ni < 4; ni++) {
            int cc = colb + ni*16;
            float cb = (BIAS_MODE == 1) ? bias[cc] : 0.f;
            #pragma unroll
            for (int rr4 = 0; rr4 < 4; rr4++) {
                int rr = rowb + mi*16 + rr4;
                float val = acc[mi][ni][rr4] * alpha + cb;
                if (BIAS_MODE == 2) val += bias[rr];
                long long idx = sCz * z + (long long)rr * ldc + cc;
                if (OUT_MODE == 0)      ((short*)Cv)[idx] = f2bf(val);
                else if (OUT_MODE == 1) ((float*)Cv)[idx] = val;
                else                    ((float*)Cv)[idx] = val + res[idx];
            }
        }
    }
}

// ---- row softmax over 4096 fp32, writes bf16 in place at row head ----
__global__ void softmax_rows(float* __restrict__ S) {
    const int tid = threadIdx.x;
    float* row = S + (size_t)blockIdx.x * N_;
    const float4* rv = (const float4*)row;
    float4 v[4];
    float mx = -3.0e38f;
    #pragma unroll
    for (int i = 0; i < 4; i++) {
        v[i] = rv[tid*4 + i];
        mx = fmaxf(mx, fmaxf(fmaxf(v[i].x, v[i].y), fmaxf(v[i].z, v[i].w)));
    }
    __shared__ float red[256];
    red[tid] = mx; __syncthreads();
    for (int h = 128; h > 0; h >>= 1) { if (tid < h) red[tid] = fmaxf(red[tid], red[tid+h]); __syncthreads(); }
    mx = red[0]; __syncthreads();
    float f[16]; float sum = 0.f;
    #pragma unroll
    for (int i = 0; i < 4; i++) {
        f[i*4+0] = __expf(v[i].x - mx);
        f[i*4+1] = __expf(v[i].y - mx);
        f[i*4+2] = __expf(v[i].z - mx);
        f[i*4+3] = __expf(v[i].w - mx);
        sum += f[i*4+0] + f[i*4+1] + f[i*4+2] + f[i*4+3];
    }
    red[tid] = sum; __syncthreads();
    for (int h = 128; h > 0; h >>= 1) { if (tid < h) red[tid] += red[tid+h]; __syncthreads(); }
    float inv = 1.f / red[0];
    short* ob = (short*)row;
    short8 o0, o1;
    #pragma unroll
    for (int j = 0; j < 8; j++) o0[j] = f2bf(f[j] * inv);
    #pragma unroll
    for (int j = 0; j < 8; j++) o1[j] = f2bf(f[8+j] * inv);
    *(short8*)&ob[tid*16]     = o0;
    *(short8*)&ob[tid*16 + 8] = o1;
}

extern "C" void kernel_launch(void* const* d_in, const int* in_sizes, int n_in,
                              void* d_out, int out_size, void* d_ws, size_t ws_size,
                              hipStream_t stream) {
    const float* x   = (const float*)d_in[0];
    const float* gnw = (const float*)d_in[1];
    const float* gnb = (const float*)d_in[2];
    const float* wq  = (const float*)d_in[3];
    const float* bq  = (const float*)d_in[4];
    const float* wk  = (const float*)d_in[5];
    const float* bk  = (const float*)d_in[6];
    const float* wv  = (const float*)d_in[7];
    const float* bv  = (const float*)d_in[8];
    const float* wp  = (const float*)d_in[9];
    const float* bp  = (const float*)d_in[10];
    float* out = (float*)d_out;
    char*  ws  = (char*)d_ws;

    // workspace layout (~108 MB total)
    float* stats = (float*)(ws + 0);                 // 512 B
    short* Wb    = (short*)(ws + 4096);              // 2 MB  [4][512][512] bf16
    short* Hn    = (short*)(ws + (4ull  << 20));     // 8 MB  [2][4096][512] bf16
    short* Qt    = (short*)(ws + (12ull << 20));     // 8 MB  [2][4096][512]
    short* Kt    = (short*)(ws + (20ull << 20));     // 8 MB  [2][4096][512]
    short* Vc    = (short*)(ws + (28ull << 20));     // 8 MB  [2][512][4096]
    short* Ot    = (short*)(ws + (36ull << 20));     // 8 MB  [2][4096][512]
    float* Sb    = (float*)(ws + (44ull << 20));     // 64 MB [4096][4096] fp32 (reused per batch)

    const int WN = C_ * C_;                          // 262144
    cvt_bf16<<<WN/256, 256, 0, stream>>>(wq, Wb + 0*WN, WN);
    cvt_bf16<<<WN/256, 256, 0, stream>>>(wk, Wb + 1*WN, WN);
    cvt_bf16<<<WN/256, 256, 0, stream>>>(wv, Wb + 2*WN, WN);
    cvt_bf16<<<WN/256, 256, 0, stream>>>(wp, Wb + 3*WN, WN);

    gn_stats<<<B_*G_, 256, 0, stream>>>(x, stats);
    gn_apply<<<dim3(N_/64, C_/64, B_), 256, 0, stream>>>(x, stats, gnw, gnb, Hn);

    const long long sBN = (long long)N_ * C_;        // per-batch plane, elements

    // Q,K: [4096,512] = Hn @ W^T + b (bias per col = out channel)
    gemm_nt<128,1,0><<<dim3(4, 32, 2), 256, 0, stream>>>(Hn, C_, sBN, Wb + 0*WN, C_, 0, Qt, C_, sBN, bq, nullptr, 1.f, C_);
    gemm_nt<128,1,0><<<dim3(4, 32, 2), 256, 0, stream>>>(Hn, C_, sBN, Wb + 1*WN, C_, 0, Kt, C_, sBN, bk, nullptr, 1.f, C_);
    // V: [512,4096] = Wv @ Hn^T + bv (bias per row = out channel)
    gemm_nt<128,2,0><<<dim3(32, 4, 2), 256, 0, stream>>>(Wb + 2*WN, C_, 0, Hn, C_, sBN, Vc, N_, sBN, bv, nullptr, 1.f, C_);

    const float scale = 0.044194173824159216f;       // 512^-0.5
    for (int b = 0; b < 2; ++b) {
        // S = Qt @ Kt^T * scale  (fp32, [4096,4096])
        gemm_nt<128,0,1><<<dim3(32, 32, 1), 256, 0, stream>>>(Qt + b*sBN, C_, 0, Kt + b*sBN, C_, 0, Sb, N_, 0, nullptr, nullptr, scale, C_);
        // softmax rows, bf16 in place (row stride stays 8192 bf16 elems)
        softmax_rows<<<N_, 256, 0, stream>>>(Sb);
        // Ot = P @ Vc^T : [4096,512], BM=64 tile -> 256 blocks (full chip)
        gemm_nt<64,0,0><<<dim3(4, 64, 1), 256, 0, stream>>>((const short*)Sb, 2*N_, 0, Vc + b*sBN, N_, 0, Ot + b*sBN, C_, 0, nullptr, nullptr, 1.f, N_);
    }

    // out[b,o,n] = x + Wp @ Ot^T + bp  (fp32, coalesced along n)
    gemm_nt<128,2,2><<<dim3(32, 4, 2), 256, 0, stream>>>(Wb + 3*WN, C_, 0, Ot, C_, sBN, out, N_, sBN, bp, x, 1.f, C_);
}

// Round 3
// 381.918 us; speedup vs baseline: 1.1494x; 1.0357x over previous
//
#include <hip/hip_runtime.h>
#include <hip/hip_bf16.h>
#include <stdint.h>

typedef short short8 __attribute__((ext_vector_type(8)));
typedef float f32x4  __attribute__((ext_vector_type(4)));

#define B_ 2
#define C_ 512
#define N_ 4096
#define G_ 32

static __device__ __forceinline__ short f2bf(float f) {
    return __builtin_bit_cast(short, __float2bfloat16(f));
}

// ---- fp32 -> bf16 weight convert ----
__global__ void cvt_bf16(const float* __restrict__ src, short* __restrict__ dst, int n) {
    int i = blockIdx.x * 256 + threadIdx.x;
    if (i < n) dst[i] = f2bf(src[i]);
}

// ---- pack bq|bk into one 1024-float bias vector ----
__global__ void pack_bias(const float* __restrict__ bq, const float* __restrict__ bk,
                          float* __restrict__ dst) {
    int i = blockIdx.x * 256 + threadIdx.x;   // 0..1023
    dst[i] = (i < C_) ? bq[i] : bk[i - C_];
}

// ---- groupnorm stats: one block per (b,g) ----
__global__ void gn_stats(const float* __restrict__ x, float* __restrict__ stats) {
    const float4* p = (const float4*)(x + (size_t)blockIdx.x * 16 * N_);
    int tid = threadIdx.x;
    float s = 0.f, sq = 0.f;
    for (int i = tid; i < (16 * N_) / 4; i += 256) {
        float4 t = p[i];
        s  += t.x + t.y + t.z + t.w;
        sq += t.x*t.x + t.y*t.y + t.z*t.z + t.w*t.w;
    }
    __shared__ float rs[256], rq[256];
    rs[tid] = s; rq[tid] = sq;
    __syncthreads();
    for (int h = 128; h > 0; h >>= 1) {
        if (tid < h) { rs[tid] += rs[tid+h]; rq[tid] += rq[tid+h]; }
        __syncthreads();
    }
    if (tid == 0) {
        float mean = rs[0] / (16.f * N_);
        float var  = rq[0] / (16.f * N_) - mean * mean;
        stats[blockIdx.x*2+0] = mean;
        stats[blockIdx.x*2+1] = rsqrtf(var + 1e-6f);
    }
}

// ---- groupnorm apply + transpose: x[b,c,n] fp32 -> Hn[b,n,c] bf16 ----
__global__ void gn_apply(const float* __restrict__ x, const float* __restrict__ stats,
                         const float* __restrict__ gw, const float* __restrict__ gb,
                         short* __restrict__ hn) {
    __shared__ short t[64 * 68];
    const int n0 = blockIdx.x * 64, c0 = blockIdx.y * 64, b = blockIdx.z;
    const int lane = threadIdx.x & 63, w = threadIdx.x >> 6;
    #pragma unroll
    for (int rep = 0; rep < 16; rep++) {
        int c  = rep * 4 + w;
        int cc = c0 + c;
        int g  = cc >> 4;
        float mean = stats[(b*G_ + g)*2 + 0];
        float rstd = stats[(b*G_ + g)*2 + 1];
        float sc = gw[cc] * rstd;
        float bi = gb[cc] - mean * sc;
        float v = x[((size_t)(b*C_ + cc)) * N_ + n0 + lane];
        t[lane*68 + c] = f2bf(v * sc + bi);
    }
    __syncthreads();
    #pragma unroll
    for (int rep = 0; rep < 16; rep++) {
        int n = rep * 4 + w;
        hn[((size_t)(b*N_ + n0 + n)) * C_ + c0 + lane] = t[n*68 + lane];
    }
}

// ---- generic NT GEMM, pipelined ----
// C[m,n] = alpha * sum_k A[m,k]*B[n,k] (+bias) (+residual)
// Register-staged global loads, double-buffered LDS, ONE barrier per BK=32 step,
// loads issued 2 tiles ahead (waited one full compute phase after issue).
// XOR-swizzled LDS (stride 32 shorts): writer (row r, chunk cs) puts global
// chunk cs at slot cs^((r>>1)&3); reader un-swizzles with the same formula.
// BIAS_MODE: 0 none, 1 per-col, 2 per-row. OUT_MODE: 0 bf16, 1 fp32, 2 fp32+res.
// BM in {64,128}; BN=128. 4 waves (2x2), wave tile (BM/2) x 64.
template<int BM, int BIAS_MODE, int OUT_MODE>
__global__ __launch_bounds__(256, 2)
void gemm_nt(const short* __restrict__ A, int lda, long long sAz,
             const short* __restrict__ Bm, int ldb, long long sBz,
             void* __restrict__ Cv, int ldc, long long sCz,
             const float* __restrict__ bias,
             const float* __restrict__ res,
             float alpha, int K) {
    constexpr int MI = BM / 32;              // 4 for BM=128, 2 for BM=64
    __shared__ short As[2][BM * 32];
    __shared__ short Bs[2][128 * 32];
    const int tid  = threadIdx.x;
    const int lane = tid & 63;
    const int wid  = tid >> 6;
    const int wr   = wid >> 1;
    const int wc   = wid & 1;
    const int m0 = blockIdx.y * BM;
    const int n0 = blockIdx.x * 128;
    const int z  = blockIdx.z;

    // staging: thread t -> row r = t>>2, global chunk cs = t&3 (coalesced read),
    // LDS slot = cs ^ ((r>>1)&3)
    const int r   = tid >> 2;                // 0..63
    const int cs  = tid & 3;
    const int swo = ((cs ^ ((r >> 1) & 3)) << 3) + r * 32;  // short offset in LDS tile

    const short* Ap  = A  + sAz * z + (long long)(m0 + r) * lda + cs * 8;
    const short* Bp  = Bm + sBz * z + (long long)(n0 + r) * ldb + cs * 8;
    const short* Ap1 = Ap + (long long)64 * lda;
    const short* Bp1 = Bp + (long long)64 * ldb;

    f32x4 acc[MI][4];
    #pragma unroll
    for (int i = 0; i < MI; i++)
        #pragma unroll
        for (int j = 0; j < 4; j++)
            acc[i][j] = f32x4{0.f, 0.f, 0.f, 0.f};

    const int fm  = lane & 15;
    const int q   = lane >> 4;                     // k-chunk 0..3
    const int swz = ((q ^ ((fm >> 1) & 3)) << 3);  // un-swizzle read offset

    short8 ga0, ga1, gb0, gb1;
    #define LOADG(k)  do { ga0 = *(const short8*)(Ap + (k)); \
                           if (BM == 128) ga1 = *(const short8*)(Ap1 + (k)); \
                           gb0 = *(const short8*)(Bp + (k)); \
                           gb1 = *(const short8*)(Bp1 + (k)); } while (0)
    #define STORES(b) do { *(short8*)&As[b][swo] = ga0; \
                           if (BM == 128) *(short8*)&As[b][swo + 64*32] = ga0*0 + ga1; \
                           *(short8*)&Bs[b][swo] = gb0; \
                           *(short8*)&Bs[b][swo + 64*32] = gb1; } while (0)
    #define COMPUTE(b) do { \
        short8 af[MI], bf[4]; \
        _Pragma("unroll") \
        for (int i = 0; i < MI; i++) af[i] = *(const short8*)&As[b][(wr*(BM/2) + i*16 + fm)*32 + swz]; \
        _Pragma("unroll") \
        for (int i = 0; i < 4; i++)  bf[i] = *(const short8*)&Bs[b][(wc*64 + i*16 + fm)*32 + swz]; \
        _Pragma("unroll") \
        for (int mi = 0; mi < MI; mi++) \
            _Pragma("unroll") \
            for (int ni = 0; ni < 4; ni++) \
                acc[mi][ni] = __builtin_amdgcn_mfma_f32_16x16x32_bf16(af[mi], bf[ni], acc[mi][ni], 0, 0, 0); \
    } while (0)

    // prologue: tile0 -> buf0, tile1 in flight
    LOADG(0);
    STORES(0);
    LOADG(32);
    __syncthreads();

    for (int k0 = 0; k0 < K; k0 += 64) {
        // stage A: compute tile k0 from buf0; store tile k0+32 -> buf1; load k0+64
        {
            short8 af[MI], bf[4];
            #pragma unroll
            for (int i = 0; i < MI; i++) af[i] = *(const short8*)&As[0][(wr*(BM/2) + i*16 + fm)*32 + swz];
            #pragma unroll
            for (int i = 0; i < 4; i++)  bf[i] = *(const short8*)&Bs[0][(wc*64 + i*16 + fm)*32 + swz];
            STORES(1);
            if (k0 + 64 < K) LOADG(k0 + 64);
            #pragma unroll
            for (int mi = 0; mi < MI; mi++)
                #pragma unroll
                for (int ni = 0; ni < 4; ni++)
                    acc[mi][ni] = __builtin_amdgcn_mfma_f32_16x16x32_bf16(af[mi], bf[ni], acc[mi][ni], 0, 0, 0);
        }
        __syncthreads();
        // stage B: compute tile k0+32 from buf1; store tile k0+64 -> buf0; load k0+96
        {
            short8 af[MI], bf[4];
            #pragma unroll
            for (int i = 0; i < MI; i++) af[i] = *(const short8*)&As[1][(wr*(BM/2) + i*16 + fm)*32 + swz];
            #pragma unroll
            for (int i = 0; i < 4; i++)  bf[i] = *(const short8*)&Bs[1][(wc*64 + i*16 + fm)*32 + swz];
            if (k0 + 64 < K) {
                STORES(0);
                if (k0 + 96 < K) LOADG(k0 + 96);
            }
            #pragma unroll
            for (int mi = 0; mi < MI; mi++)
                #pragma unroll
                for (int ni = 0; ni < 4; ni++)
                    acc[mi][ni] = __builtin_amdgcn_mfma_f32_16x16x32_bf16(af[mi], bf[ni], acc[mi][ni], 0, 0, 0);
        }
        __syncthreads();
    }
    #undef LOADG
    #undef STORES
    #undef COMPUTE

    const int colb = n0 + wc*64 + fm;
    const int rowb = m0 + wr*(BM/2) + (q << 2);
    #pragma unroll
    for (int mi = 0; mi < MI; mi++) {
        #pragma unroll
        for (int ni = 0; ni < 4; ni++) {
            int cc = colb + ni*16;
            float cb = (BIAS_MODE == 1) ? bias[cc] : 0.f;
            #pragma unroll
            for (int rr4 = 0; rr4 < 4; rr4++) {
                int rr = rowb + mi*16 + rr4;
                float val = acc[mi][ni][rr4] * alpha + cb;
                if (BIAS_MODE == 2) val += bias[rr];
                long long idx = sCz * z + (long long)rr * ldc + cc;
                if (OUT_MODE == 0)      ((short*)Cv)[idx] = f2bf(val);
                else if (OUT_MODE == 1) ((float*)Cv)[idx] = val;
                else                    ((float*)Cv)[idx] = val + res[idx];
            }
        }
    }
}

// ---- row softmax over 4096 fp32, writes bf16 in place at row head ----
__global__ void softmax_rows(float* __restrict__ S) {
    const int tid = threadIdx.x;
    float* row = S + (size_t)blockIdx.x * N_;
    const float4* rv = (const float4*)row;
    float4 v[4];
    float mx = -3.0e38f;
    #pragma unroll
    for (int i = 0; i < 4; i++) {
        v[i] = rv[tid*4 + i];
        mx = fmaxf(mx, fmaxf(fmaxf(v[i].x, v[i].y), fmaxf(v[i].z, v[i].w)));
    }
    __shared__ float red[256];
    red[tid] = mx; __syncthreads();
    for (int h = 128; h > 0; h >>= 1) { if (tid < h) red[tid] = fmaxf(red[tid], red[tid+h]); __syncthreads(); }
    mx = red[0]; __syncthreads();
    float f[16]; float sum = 0.f;
    #pragma unroll
    for (int i = 0; i < 4; i++) {
        f[i*4+0] = __expf(v[i].x - mx);
        f[i*4+1] = __expf(v[i].y - mx);
        f[i*4+2] = __expf(v[i].z - mx);
        f[i*4+3] = __expf(v[i].w - mx);
        sum += f[i*4+0] + f[i*4+1] + f[i*4+2] + f[i*4+3];
    }
    red[tid] = sum; __syncthreads();
    for (int h = 128; h > 0; h >>= 1) { if (tid < h) red[tid] += red[tid+h]; __syncthreads(); }
    float inv = 1.f / red[0];
    short* ob = (short*)row;
    short8 o0, o1;
    #pragma unroll
    for (int j = 0; j < 8; j++) o0[j] = f2bf(f[j] * inv);
    #pragma unroll
    for (int j = 0; j < 8; j++) o1[j] = f2bf(f[8+j] * inv);
    *(short8*)&ob[tid*16]     = o0;
    *(short8*)&ob[tid*16 + 8] = o1;
}

// ---- reduce 4 split-K fp32 partials -> bf16 Ot[4096][512] ----
// partial(s,i,c) at p[i*4096 + s*512 + c]
__global__ void reduce4(const float* __restrict__ p, short* __restrict__ o) {
    int idx = blockIdx.x * 256 + threadIdx.x;   // 0 .. 512K-1, 4 c's each
    int i  = idx >> 7;
    int cg = (idx & 127) << 2;
    const float4* b = (const float4*)(p + (size_t)i * 4096 + cg);
    float4 s0 = b[0], s1 = b[128], s2 = b[256], s3 = b[384];
    float4 t;
    t.x = s0.x + s1.x + s2.x + s3.x;
    t.y = s0.y + s1.y + s2.y + s3.y;
    t.z = s0.z + s1.z + s2.z + s3.z;
    t.w = s0.w + s1.w + s2.w + s3.w;
    short4 r;
    r.x = f2bf(t.x); r.y = f2bf(t.y); r.z = f2bf(t.z); r.w = f2bf(t.w);
    *(short4*)&o[(size_t)i * C_ + cg] = r;
}

extern "C" void kernel_launch(void* const* d_in, const int* in_sizes, int n_in,
                              void* d_out, int out_size, void* d_ws, size_t ws_size,
                              hipStream_t stream) {
    const float* x   = (const float*)d_in[0];
    const float* gnw = (const float*)d_in[1];
    const float* gnb = (const float*)d_in[2];
    const float* wq  = (const float*)d_in[3];
    const float* bq  = (const float*)d_in[4];
    const float* wk  = (const float*)d_in[5];
    const float* bk  = (const float*)d_in[6];
    const float* wv  = (const float*)d_in[7];
    const float* bv  = (const float*)d_in[8];
    const float* wp  = (const float*)d_in[9];
    const float* bp  = (const float*)d_in[10];
    float* out = (float*)d_out;
    char*  ws  = (char*)d_ws;

    // workspace layout (~108 MB, same footprint as round 2)
    float* stats = (float*)(ws + 0);                 // 512 B
    float* bqk   = (float*)(ws + 8192);              // 4 KB [1024]
    short* Wb    = (short*)(ws + 65536);             // 2 MB  [4][512][512] bf16 (Wq,Wk adjacent)
    short* Hn    = (short*)(ws + (4ull  << 20));     // 8 MB  [2][4096][512] bf16
    short* QKt   = (short*)(ws + (12ull << 20));     // 16 MB [2][4096][1024] (Q cols 0-511, K 512-1023)
    short* Vc    = (short*)(ws + (28ull << 20));     // 8 MB  [2][512][4096]
    short* Ot    = (short*)(ws + (36ull << 20));     // 8 MB  [2][4096][512]
    float* Sb    = (float*)(ws + (44ull << 20));     // 64 MB [4096][4096] fp32 (reused per batch)
    float* Pp    = Sb + 2048;                        // split-K partials live in the unused
                                                     // second half of each 16 KB Sb row

    const int WN = C_ * C_;
    cvt_bf16<<<WN/256, 256, 0, stream>>>(wq, Wb + 0*WN, WN);
    cvt_bf16<<<WN/256, 256, 0, stream>>>(wk, Wb + 1*WN, WN);
    cvt_bf16<<<WN/256, 256, 0, stream>>>(wv, Wb + 2*WN, WN);
    cvt_bf16<<<WN/256, 256, 0, stream>>>(wp, Wb + 3*WN, WN);
    pack_bias<<<4, 256, 0, stream>>>(bq, bk, bqk);

    gn_stats<<<B_*G_, 256, 0, stream>>>(x, stats);
    gn_apply<<<dim3(N_/64, C_/64, B_), 256, 0, stream>>>(x, stats, gnw, gnb, Hn);

    const long long sBN = (long long)N_ * C_;        // 4096*512

    // QK fused: [4096,1024] = Hn @ [Wq;Wk]^T + bqk   (512 blocks, 2/CU)
    gemm_nt<128,1,0><<<dim3(8, 32, 2), 256, 0, stream>>>(
        Hn, C_, sBN, Wb, C_, 0, QKt, 1024, (long long)N_*1024, bqk, nullptr, 1.f, C_);
    // V: [512,4096] = Wv @ Hn^T + bv   (BM=64 -> 512 blocks)
    gemm_nt<64,2,0><<<dim3(32, 8, 2), 256, 0, stream>>>(
        Wb + 2*WN, C_, 0, Hn, C_, sBN, Vc, N_, sBN, bv, nullptr, 1.f, C_);

    const float scale = 0.044194173824159216f;       // 512^-0.5
    for (int b = 0; b < 2; ++b) {
        const short* Qb = QKt + (long long)b * N_ * 1024;
        const short* Kb = Qb + 512;
        // S = Q @ K^T * scale  (fp32 [4096,4096], 1024 blocks)
        gemm_nt<128,0,1><<<dim3(32, 32, 1), 256, 0, stream>>>(
            Qb, 1024, 0, Kb, 1024, 0, Sb, N_, 0, nullptr, nullptr, scale, C_);
        // softmax rows -> bf16 P in place (row stride 8192 shorts)
        softmax_rows<<<N_, 256, 0, stream>>>(Sb);
        // PV split-K x4: partials fp32 into row second-halves (512 blocks, 2/CU)
        gemm_nt<128,0,1><<<dim3(4, 32, 4), 256, 0, stream>>>(
            (const short*)Sb, 2*N_, 1024, Vc + b*sBN, N_, 1024, Pp, N_, 512,
            nullptr, nullptr, 1.f, 1024);
        // reduce partials -> Ot bf16
        reduce4<<<2048, 256, 0, stream>>>(Pp, Ot + b*sBN);
    }

    // out[b,o,n] = x + Wp @ Ot^T + bp  (BM=64 -> 512 blocks)
    gemm_nt<64,2,2><<<dim3(32, 8, 2), 256, 0, stream>>>(
        Wb + 3*WN, C_, 0, Ot, C_, sBN, out, N_, (long long)C_*N_, bp, x, 1.f, C_);
}

// Round 4
// 281.871 us; speedup vs baseline: 1.5574x; 1.3549x over previous
//
#include <hip/hip_runtime.h>
#include <hip/hip_bf16.h>
#include <stdint.h>

typedef short short8 __attribute__((ext_vector_type(8)));
typedef float f32x4  __attribute__((ext_vector_type(4)));

#define B_ 2
#define C_ 512
#define N_ 4096
#define G_ 32
#define WN (C_ * C_)

static __device__ __forceinline__ short f2bf(float f) {
    return __builtin_bit_cast(short, __float2bfloat16(f));
}

// ---- fused prep: bf16-convert 4 weights, pack bq|bk, zero gn accumulators ----
__global__ void prep(const float* __restrict__ wq, const float* __restrict__ wk,
                     const float* __restrict__ wv, const float* __restrict__ wp,
                     const float* __restrict__ bq, const float* __restrict__ bk,
                     short* __restrict__ Wb, float* __restrict__ bqk,
                     float* __restrict__ raw) {
    int i = blockIdx.x * 256 + threadIdx.x;
    if (i < 4 * WN) {
        const float* src = (i < 2*WN) ? ((i < WN) ? wq : wk) : ((i < 3*WN) ? wv : wp);
        Wb[i] = f2bf(src[i & (WN - 1)]);
    } else if (i < 4*WN + 1024) {
        int j = i - 4*WN;
        bqk[j] = (j < C_) ? bq[j] : bk[j - C_];
    } else if (i < 4*WN + 1024 + 128) {
        raw[i - (4*WN + 1024)] = 0.f;
    }
}

// ---- gn partial stats: 4 blocks per (b,g), atomicAdd raw sums ----
__global__ void gn_stats(const float* __restrict__ x, float* __restrict__ raw) {
    const int bg = blockIdx.x >> 2, qt = blockIdx.x & 3;
    const float4* p = (const float4*)(x + (size_t)bg * 16 * N_ + (size_t)qt * 4 * N_);
    int tid = threadIdx.x;
    float s = 0.f, sq = 0.f;
    #pragma unroll
    for (int rep = 0; rep < 16; rep++) {
        float4 t = p[rep * 256 + tid];
        s  += t.x + t.y + t.z + t.w;
        sq += t.x*t.x + t.y*t.y + t.z*t.z + t.w*t.w;
    }
    __shared__ float rs[256], rq[256];
    rs[tid] = s; rq[tid] = sq;
    __syncthreads();
    for (int h = 128; h > 0; h >>= 1) {
        if (tid < h) { rs[tid] += rs[tid+h]; rq[tid] += rq[tid+h]; }
        __syncthreads();
    }
    if (tid == 0) {
        atomicAdd(&raw[bg*2+0], rs[0]);
        atomicAdd(&raw[bg*2+1], rq[0]);
    }
}

// ---- groupnorm apply + transpose: x[b,c,n] fp32 -> Hn[b,n,c] bf16 ----
__global__ void gn_apply(const float* __restrict__ x, const float* __restrict__ raw,
                         const float* __restrict__ gw, const float* __restrict__ gb,
                         short* __restrict__ hn) {
    __shared__ short t[64 * 68];
    const int n0 = blockIdx.x * 64, c0 = blockIdx.y * 64, b = blockIdx.z;
    const int lane = threadIdx.x & 63, w = threadIdx.x >> 6;
    const float inv = 1.f / (16.f * N_);
    #pragma unroll
    for (int rep = 0; rep < 16; rep++) {
        int c  = rep * 4 + w;
        int cc = c0 + c;
        int g  = cc >> 4;
        float mean = raw[(b*G_ + g)*2 + 0] * inv;
        float var  = raw[(b*G_ + g)*2 + 1] * inv - mean * mean;
        float rstd = rsqrtf(var + 1e-6f);
        float sc = gw[cc] * rstd;
        float bi = gb[cc] - mean * sc;
        float v = x[((size_t)(b*C_ + cc)) * N_ + n0 + lane];
        t[lane*68 + c] = f2bf(v * sc + bi);
    }
    __syncthreads();
    #pragma unroll
    for (int rep = 0; rep < 16; rep++) {
        int n = rep * 4 + w;
        hn[((size_t)(b*N_ + n0 + n)) * C_ + c0 + lane] = t[n*68 + lane];
    }
}

// ---- generic NT GEMM, pipelined (reg-staged dbuf LDS, 1 barrier / BK=32) ----
// C[m,n] = alpha * sum_k A[m,k]*B[n,k] (+bias) (+residual)
// XOR-swizzled LDS (stride 32 shorts). BIAS_MODE: 0 none, 1 per-col, 2 per-row.
// OUT_MODE: 0 bf16, 1 fp32, 2 fp32+res. BM in {64,128}; BN=128; 4 waves (2x2).
template<int BM, int BIAS_MODE, int OUT_MODE>
__global__ __launch_bounds__(256, 2)
void gemm_nt(const short* __restrict__ A, int lda, long long sAz,
             const short* __restrict__ Bm, int ldb, long long sBz,
             void* __restrict__ Cv, int ldc, long long sCz,
             const float* __restrict__ bias,
             const float* __restrict__ res,
             float alpha, int K) {
    constexpr int MI = BM / 32;
    __shared__ short As[2][BM * 32];
    __shared__ short Bs[2][128 * 32];
    const int tid  = threadIdx.x;
    const int lane = tid & 63;
    const int wid  = tid >> 6;
    const int wr   = wid >> 1;
    const int wc   = wid & 1;
    const int m0 = blockIdx.y * BM;
    const int n0 = blockIdx.x * 128;
    const int z  = blockIdx.z;

    const int r   = tid >> 2;
    const int cs  = tid & 3;
    const int swo = ((cs ^ ((r >> 1) & 3)) << 3) + r * 32;

    const short* Ap  = A  + sAz * z + (long long)(m0 + r) * lda + cs * 8;
    const short* Bp  = Bm + sBz * z + (long long)(n0 + r) * ldb + cs * 8;
    const short* Ap1 = Ap + (long long)64 * lda;
    const short* Bp1 = Bp + (long long)64 * ldb;

    f32x4 acc[MI][4];
    #pragma unroll
    for (int i = 0; i < MI; i++)
        #pragma unroll
        for (int j = 0; j < 4; j++)
            acc[i][j] = f32x4{0.f, 0.f, 0.f, 0.f};

    const int fm  = lane & 15;
    const int q   = lane >> 4;
    const int swz = ((q ^ ((fm >> 1) & 3)) << 3);

    short8 ga0, ga1, gb0, gb1;
    #define LOADG(k)  do { ga0 = *(const short8*)(Ap + (k)); \
                           if (BM == 128) ga1 = *(const short8*)(Ap1 + (k)); \
                           gb0 = *(const short8*)(Bp + (k)); \
                           gb1 = *(const short8*)(Bp1 + (k)); } while (0)
    #define STORES(b) do { *(short8*)&As[b][swo] = ga0; \
                           if (BM == 128) *(short8*)&As[b][swo + 64*32] = ga1; \
                           *(short8*)&Bs[b][swo] = gb0; \
                           *(short8*)&Bs[b][swo + 64*32] = gb1; } while (0)

    LOADG(0);
    STORES(0);
    LOADG(32);
    __syncthreads();

    for (int k0 = 0; k0 < K; k0 += 64) {
        {
            short8 af[MI], bf[4];
            #pragma unroll
            for (int i = 0; i < MI; i++) af[i] = *(const short8*)&As[0][(wr*(BM/2) + i*16 + fm)*32 + swz];
            #pragma unroll
            for (int i = 0; i < 4; i++)  bf[i] = *(const short8*)&Bs[0][(wc*64 + i*16 + fm)*32 + swz];
            STORES(1);
            if (k0 + 64 < K) LOADG(k0 + 64);
            #pragma unroll
            for (int mi = 0; mi < MI; mi++)
                #pragma unroll
                for (int ni = 0; ni < 4; ni++)
                    acc[mi][ni] = __builtin_amdgcn_mfma_f32_16x16x32_bf16(af[mi], bf[ni], acc[mi][ni], 0, 0, 0);
        }
        __syncthreads();
        {
            short8 af[MI], bf[4];
            #pragma unroll
            for (int i = 0; i < MI; i++) af[i] = *(const short8*)&As[1][(wr*(BM/2) + i*16 + fm)*32 + swz];
            #pragma unroll
            for (int i = 0; i < 4; i++)  bf[i] = *(const short8*)&Bs[1][(wc*64 + i*16 + fm)*32 + swz];
            if (k0 + 64 < K) {
                STORES(0);
                if (k0 + 96 < K) LOADG(k0 + 96);
            }
            #pragma unroll
            for (int mi = 0; mi < MI; mi++)
                #pragma unroll
                for (int ni = 0; ni < 4; ni++)
                    acc[mi][ni] = __builtin_amdgcn_mfma_f32_16x16x32_bf16(af[mi], bf[ni], acc[mi][ni], 0, 0, 0);
        }
        __syncthreads();
    }
    #undef LOADG
    #undef STORES

    const int colb = n0 + wc*64 + fm;
    const int rowb = m0 + wr*(BM/2) + (q << 2);
    #pragma unroll
    for (int mi = 0; mi < MI; mi++) {
        #pragma unroll
        for (int ni = 0; ni < 4; ni++) {
            int cc = colb + ni*16;
            float cb = (BIAS_MODE == 1) ? bias[cc] : 0.f;
            #pragma unroll
            for (int rr4 = 0; rr4 < 4; rr4++) {
                int rr = rowb + mi*16 + rr4;
                float val = acc[mi][ni][rr4] * alpha + cb;
                if (BIAS_MODE == 2) val += bias[rr];
                long long idx = sCz * z + (long long)rr * ldc + cc;
                if (OUT_MODE == 0)      ((short*)Cv)[idx] = f2bf(val);
                else if (OUT_MODE == 1) ((float*)Cv)[idx] = val;
                else                    ((float*)Cv)[idx] = val + res[idx];
            }
        }
    }
}

// ---- row softmax over 4096 fp32, bf16 in place; both batches via grid.x ----
__global__ void softmax_rows(float* __restrict__ S) {
    const int tid = threadIdx.x;
    const int row = blockIdx.x;                 // 0..8191
    float* rp = S + (size_t)(row >> 12) * N_ * N_ + (size_t)(row & (N_-1)) * N_;
    const float4* rv = (const float4*)rp;
    float4 v[4];
    float mx = -3.0e38f;
    #pragma unroll
    for (int i = 0; i < 4; i++) {
        v[i] = rv[tid*4 + i];
        mx = fmaxf(mx, fmaxf(fmaxf(v[i].x, v[i].y), fmaxf(v[i].z, v[i].w)));
    }
    __shared__ float red[256];
    red[tid] = mx; __syncthreads();
    for (int h = 128; h > 0; h >>= 1) { if (tid < h) red[tid] = fmaxf(red[tid], red[tid+h]); __syncthreads(); }
    mx = red[0]; __syncthreads();
    float f[16]; float sum = 0.f;
    #pragma unroll
    for (int i = 0; i < 4; i++) {
        f[i*4+0] = __expf(v[i].x - mx);
        f[i*4+1] = __expf(v[i].y - mx);
        f[i*4+2] = __expf(v[i].z - mx);
        f[i*4+3] = __expf(v[i].w - mx);
        sum += f[i*4+0] + f[i*4+1] + f[i*4+2] + f[i*4+3];
    }
    red[tid] = sum; __syncthreads();
    for (int h = 128; h > 0; h >>= 1) { if (tid < h) red[tid] += red[tid+h]; __syncthreads(); }
    float inv = 1.f / red[0];
    short* ob = (short*)rp;
    short8 o0, o1;
    #pragma unroll
    for (int j = 0; j < 8; j++) o0[j] = f2bf(f[j] * inv);
    #pragma unroll
    for (int j = 0; j < 8; j++) o1[j] = f2bf(f[8+j] * inv);
    *(short8*)&ob[tid*16]     = o0;
    *(short8*)&ob[tid*16 + 8] = o1;
}

extern "C" void kernel_launch(void* const* d_in, const int* in_sizes, int n_in,
                              void* d_out, int out_size, void* d_ws, size_t ws_size,
                              hipStream_t stream) {
    const float* x   = (const float*)d_in[0];
    const float* gnw = (const float*)d_in[1];
    const float* gnb = (const float*)d_in[2];
    const float* wq  = (const float*)d_in[3];
    const float* bq  = (const float*)d_in[4];
    const float* wk  = (const float*)d_in[5];
    const float* bk  = (const float*)d_in[6];
    const float* wv  = (const float*)d_in[7];
    const float* bv  = (const float*)d_in[8];
    const float* wp  = (const float*)d_in[9];
    const float* bp  = (const float*)d_in[10];
    float* out = (float*)d_out;
    char*  ws  = (char*)d_ws;

    // workspace layout (~172 MB)
    float* raw = (float*)(ws + 0);                   // 512 B  gn accumulators
    float* bqk = (float*)(ws + 8192);                // 4 KB
    short* Wb  = (short*)(ws + 65536);               // 2 MB   [4][512][512] bf16
    short* Hn  = (short*)(ws + (4ull  << 20));       // 8 MB   [2][4096][512]
    short* QKt = (short*)(ws + (12ull << 20));       // 16 MB  [2][4096][1024]
    short* Vc  = (short*)(ws + (28ull << 20));       // 8 MB   [2][512][4096]
    short* Ot  = (short*)(ws + (36ull << 20));       // 8 MB   [2][4096][512]
    float* Sb  = (float*)(ws + (44ull << 20));       // 128 MB [2][4096][4096] fp32

    prep<<<(4*WN + 1024 + 128 + 255)/256, 256, 0, stream>>>(wq, wk, wv, wp, bq, bk, Wb, bqk, raw);
    gn_stats<<<B_*G_*4, 256, 0, stream>>>(x, raw);
    gn_apply<<<dim3(N_/64, C_/64, B_), 256, 0, stream>>>(x, raw, gnw, gnb, Hn);

    const long long sBN = (long long)N_ * C_;
    const long long sS  = (long long)N_ * N_;

    // QK fused: [4096,1024] = Hn @ [Wq;Wk]^T + bqk   (512 blocks)
    gemm_nt<128,1,0><<<dim3(8, 32, 2), 256, 0, stream>>>(
        Hn, C_, sBN, Wb, C_, 0, QKt, 1024, (long long)N_*1024, bqk, nullptr, 1.f, C_);
    // V: [512,4096] = Wv @ Hn^T + bv   (512 blocks)
    gemm_nt<64,2,0><<<dim3(32, 8, 2), 256, 0, stream>>>(
        Wb + 2*WN, C_, 0, Hn, C_, sBN, Vc, N_, sBN, bv, nullptr, 1.f, C_);

    const float scale = 0.044194173824159216f;       // 512^-0.5
    // S = Q @ K^T * scale, both batches (2048 blocks)
    gemm_nt<128,0,1><<<dim3(32, 32, 2), 256, 0, stream>>>(
        QKt, 1024, (long long)N_*1024, QKt + 512, 1024, (long long)N_*1024,
        Sb, N_, sS, nullptr, nullptr, scale, C_);
    // softmax rows -> bf16 P in place, both batches
    softmax_rows<<<B_*N_, 256, 0, stream>>>(Sb);
    // Ot = P @ Vc^T : [4096,512] bf16 direct, both batches (512 blocks)
    gemm_nt<64,0,0><<<dim3(4, 64, 2), 256, 0, stream>>>(
        (const short*)Sb, 2*N_, 2*sS, Vc, N_, sBN, Ot, C_, sBN, nullptr, nullptr, 1.f, N_);
    // out[b,o,n] = x + Wp @ Ot^T + bp   (512 blocks)
    gemm_nt<64,2,2><<<dim3(32, 8, 2), 256, 0, stream>>>(
        Wb + 3*WN, C_, 0, Ot, C_, sBN, out, N_, (long long)C_*N_, bp, x, 1.f, C_);
}

// Round 5
// 280.128 us; speedup vs baseline: 1.5670x; 1.0062x over previous
//
#include <hip/hip_runtime.h>
#include <hip/hip_bf16.h>
#include <stdint.h>

typedef short short8 __attribute__((ext_vector_type(8)));
typedef float f32x4  __attribute__((ext_vector_type(4)));

#define B_ 2
#define C_ 512
#define N_ 4096
#define G_ 32
#define WN (C_ * C_)

static __device__ __forceinline__ short f2bf(float f) {
    return __builtin_bit_cast(short, __float2bfloat16(f));
}
static __device__ __forceinline__ float bf2f(short s) {
    return __builtin_bit_cast(float, ((unsigned)(unsigned short)s) << 16);
}

// ---- fused prep: bf16-convert 4 weights, pack bq|bk, zero gn accumulators ----
__global__ void prep(const float* __restrict__ wq, const float* __restrict__ wk,
                     const float* __restrict__ wv, const float* __restrict__ wp,
                     const float* __restrict__ bq, const float* __restrict__ bk,
                     short* __restrict__ Wb, float* __restrict__ bqk,
                     float* __restrict__ raw) {
    int i = blockIdx.x * 256 + threadIdx.x;
    if (i < 4 * WN) {
        const float* src = (i < 2*WN) ? ((i < WN) ? wq : wk) : ((i < 3*WN) ? wv : wp);
        Wb[i] = f2bf(src[i & (WN - 1)]);
    } else if (i < 4*WN + 1024) {
        int j = i - 4*WN;
        bqk[j] = (j < C_) ? bq[j] : bk[j - C_];
    } else if (i < 4*WN + 1024 + 128) {
        raw[i - (4*WN + 1024)] = 0.f;
    }
}

// ---- gn partial stats: 4 blocks per (b,g), atomicAdd raw sums ----
__global__ void gn_stats(const float* __restrict__ x, float* __restrict__ raw) {
    const int bg = blockIdx.x >> 2, qt = blockIdx.x & 3;
    const float4* p = (const float4*)(x + (size_t)bg * 16 * N_ + (size_t)qt * 4 * N_);
    int tid = threadIdx.x;
    float s = 0.f, sq = 0.f;
    #pragma unroll
    for (int rep = 0; rep < 16; rep++) {
        float4 t = p[rep * 256 + tid];
        s  += t.x + t.y + t.z + t.w;
        sq += t.x*t.x + t.y*t.y + t.z*t.z + t.w*t.w;
    }
    __shared__ float rs[256], rq[256];
    rs[tid] = s; rq[tid] = sq;
    __syncthreads();
    for (int h = 128; h > 0; h >>= 1) {
        if (tid < h) { rs[tid] += rs[tid+h]; rq[tid] += rq[tid+h]; }
        __syncthreads();
    }
    if (tid == 0) {
        atomicAdd(&raw[bg*2+0], rs[0]);
        atomicAdd(&raw[bg*2+1], rq[0]);
    }
}

// ---- groupnorm apply + transpose: x[b,c,n] fp32 -> Hn[b,n,c] bf16 ----
__global__ void gn_apply(const float* __restrict__ x, const float* __restrict__ raw,
                         const float* __restrict__ gw, const float* __restrict__ gb,
                         short* __restrict__ hn) {
    __shared__ short t[64 * 68];
    const int n0 = blockIdx.x * 64, c0 = blockIdx.y * 64, b = blockIdx.z;
    const int lane = threadIdx.x & 63, w = threadIdx.x >> 6;
    const float inv = 1.f / (16.f * N_);
    #pragma unroll
    for (int rep = 0; rep < 16; rep++) {
        int c  = rep * 4 + w;
        int cc = c0 + c;
        int g  = cc >> 4;
        float mean = raw[(b*G_ + g)*2 + 0] * inv;
        float var  = raw[(b*G_ + g)*2 + 1] * inv - mean * mean;
        float rstd = rsqrtf(var + 1e-6f);
        float sc = gw[cc] * rstd;
        float bi = gb[cc] - mean * sc;
        float v = x[((size_t)(b*C_ + cc)) * N_ + n0 + lane];
        t[lane*68 + c] = f2bf(v * sc + bi);
    }
    __syncthreads();
    #pragma unroll
    for (int rep = 0; rep < 16; rep++) {
        int n = rep * 4 + w;
        hn[((size_t)(b*N_ + n0 + n)) * C_ + c0 + lane] = t[n*68 + lane];
    }
}

// ---- generic NT GEMM, pipelined (reg-staged dbuf LDS, 1 barrier / BK=32) ----
// C[m,n] = alpha * sum_k A[m,k]*B[n,k] (+bias) (+residual)
// XOR-swizzled LDS (stride 32 shorts). BIAS_MODE: 0 none, 1 per-col, 2 per-row.
// OUT_MODE: 0 bf16, 1 fp32, 2 fp32+res. BM in {64,128}; BN=128; 4 waves (2x2).
template<int BM, int BIAS_MODE, int OUT_MODE>
__global__ __launch_bounds__(256, 2)
void gemm_nt(const short* __restrict__ A, int lda, long long sAz,
             const short* __restrict__ Bm, int ldb, long long sBz,
             void* __restrict__ Cv, int ldc, long long sCz,
             const float* __restrict__ bias,
             const float* __restrict__ res,
             float alpha, int K) {
    constexpr int MI = BM / 32;
    __shared__ short As[2][BM * 32];
    __shared__ short Bs[2][128 * 32];
    const int tid  = threadIdx.x;
    const int lane = tid & 63;
    const int wid  = tid >> 6;
    const int wr   = wid >> 1;
    const int wc   = wid & 1;
    const int m0 = blockIdx.y * BM;
    const int n0 = blockIdx.x * 128;
    const int z  = blockIdx.z;

    const int r   = tid >> 2;
    const int cs  = tid & 3;
    const int swo = ((cs ^ ((r >> 1) & 3)) << 3) + r * 32;

    const short* Ap  = A  + sAz * z + (long long)(m0 + r) * lda + cs * 8;
    const short* Bp  = Bm + sBz * z + (long long)(n0 + r) * ldb + cs * 8;
    const short* Ap1 = Ap + (long long)64 * lda;
    const short* Bp1 = Bp + (long long)64 * ldb;

    f32x4 acc[MI][4];
    #pragma unroll
    for (int i = 0; i < MI; i++)
        #pragma unroll
        for (int j = 0; j < 4; j++)
            acc[i][j] = f32x4{0.f, 0.f, 0.f, 0.f};

    const int fm  = lane & 15;
    const int q   = lane >> 4;
    const int swz = ((q ^ ((fm >> 1) & 3)) << 3);

    short8 ga0, ga1, gb0, gb1;
    #define LOADG(k)  do { ga0 = *(const short8*)(Ap + (k)); \
                           if (BM == 128) ga1 = *(const short8*)(Ap1 + (k)); \
                           gb0 = *(const short8*)(Bp + (k)); \
                           gb1 = *(const short8*)(Bp1 + (k)); } while (0)
    #define STORES(b) do { *(short8*)&As[b][swo] = ga0; \
                           if (BM == 128) *(short8*)&As[b][swo + 64*32] = ga1; \
                           *(short8*)&Bs[b][swo] = gb0; \
                           *(short8*)&Bs[b][swo + 64*32] = gb1; } while (0)

    LOADG(0);
    STORES(0);
    LOADG(32);
    __syncthreads();

    for (int k0 = 0; k0 < K; k0 += 64) {
        {
            short8 af[MI], bf[4];
            #pragma unroll
            for (int i = 0; i < MI; i++) af[i] = *(const short8*)&As[0][(wr*(BM/2) + i*16 + fm)*32 + swz];
            #pragma unroll
            for (int i = 0; i < 4; i++)  bf[i] = *(const short8*)&Bs[0][(wc*64 + i*16 + fm)*32 + swz];
            STORES(1);
            if (k0 + 64 < K) LOADG(k0 + 64);
            #pragma unroll
            for (int mi = 0; mi < MI; mi++)
                #pragma unroll
                for (int ni = 0; ni < 4; ni++)
                    acc[mi][ni] = __builtin_amdgcn_mfma_f32_16x16x32_bf16(af[mi], bf[ni], acc[mi][ni], 0, 0, 0);
        }
        __syncthreads();
        {
            short8 af[MI], bf[4];
            #pragma unroll
            for (int i = 0; i < MI; i++) af[i] = *(const short8*)&As[1][(wr*(BM/2) + i*16 + fm)*32 + swz];
            #pragma unroll
            for (int i = 0; i < 4; i++)  bf[i] = *(const short8*)&Bs[1][(wc*64 + i*16 + fm)*32 + swz];
            if (k0 + 64 < K) {
                STORES(0);
                if (k0 + 96 < K) LOADG(k0 + 96);
            }
            #pragma unroll
            for (int mi = 0; mi < MI; mi++)
                #pragma unroll
                for (int ni = 0; ni < 4; ni++)
                    acc[mi][ni] = __builtin_amdgcn_mfma_f32_16x16x32_bf16(af[mi], bf[ni], acc[mi][ni], 0, 0, 0);
        }
        __syncthreads();
    }
    #undef LOADG
    #undef STORES

    const int colb = n0 + wc*64 + fm;
    const int rowb = m0 + wr*(BM/2) + (q << 2);
    #pragma unroll
    for (int mi = 0; mi < MI; mi++) {
        #pragma unroll
        for (int ni = 0; ni < 4; ni++) {
            int cc = colb + ni*16;
            float cb = (BIAS_MODE == 1) ? bias[cc] : 0.f;
            #pragma unroll
            for (int rr4 = 0; rr4 < 4; rr4++) {
                int rr = rowb + mi*16 + rr4;
                float val = acc[mi][ni][rr4] * alpha + cb;
                if (BIAS_MODE == 2) val += bias[rr];
                long long idx = sCz * z + (long long)rr * ldc + cc;
                if (OUT_MODE == 0)      ((short*)Cv)[idx] = f2bf(val);
                else if (OUT_MODE == 1) ((float*)Cv)[idx] = val;
                else                    ((float*)Cv)[idx] = val + res[idx];
            }
        }
    }
}

// ---- row softmax over 4096 bf16, in place; both batches via grid.x ----
__global__ void softmax_rows(short* __restrict__ S) {
    const int tid = threadIdx.x;
    short* rp = S + (size_t)blockIdx.x * N_;
    short8 a = ((const short8*)rp)[tid*2];
    short8 b = ((const short8*)rp)[tid*2 + 1];
    float f[16];
    float mx = -3.0e38f;
    #pragma unroll
    for (int j = 0; j < 8; j++) { f[j]   = bf2f(a[j]); mx = fmaxf(mx, f[j]); }
    #pragma unroll
    for (int j = 0; j < 8; j++) { f[8+j] = bf2f(b[j]); mx = fmaxf(mx, f[8+j]); }
    __shared__ float red[256];
    red[tid] = mx; __syncthreads();
    for (int h = 128; h > 0; h >>= 1) { if (tid < h) red[tid] = fmaxf(red[tid], red[tid+h]); __syncthreads(); }
    mx = red[0]; __syncthreads();
    float sum = 0.f;
    #pragma unroll
    for (int j = 0; j < 16; j++) { f[j] = __expf(f[j] - mx); sum += f[j]; }
    red[tid] = sum; __syncthreads();
    for (int h = 128; h > 0; h >>= 1) { if (tid < h) red[tid] += red[tid+h]; __syncthreads(); }
    float inv = 1.f / red[0];
    short8 o0, o1;
    #pragma unroll
    for (int j = 0; j < 8; j++) o0[j] = f2bf(f[j] * inv);
    #pragma unroll
    for (int j = 0; j < 8; j++) o1[j] = f2bf(f[8+j] * inv);
    ((short8*)rp)[tid*2]     = o0;
    ((short8*)rp)[tid*2 + 1] = o1;
}

extern "C" void kernel_launch(void* const* d_in, const int* in_sizes, int n_in,
                              void* d_out, int out_size, void* d_ws, size_t ws_size,
                              hipStream_t stream) {
    const float* x   = (const float*)d_in[0];
    const float* gnw = (const float*)d_in[1];
    const float* gnb = (const float*)d_in[2];
    const float* wq  = (const float*)d_in[3];
    const float* bq  = (const float*)d_in[4];
    const float* wk  = (const float*)d_in[5];
    const float* bk  = (const float*)d_in[6];
    const float* wv  = (const float*)d_in[7];
    const float* bv  = (const float*)d_in[8];
    const float* wp  = (const float*)d_in[9];
    const float* bp  = (const float*)d_in[10];
    float* out = (float*)d_out;
    char*  ws  = (char*)d_ws;

    // workspace layout (~108 MB)
    float* raw = (float*)(ws + 0);                   // 512 B  gn accumulators
    float* bqk = (float*)(ws + 8192);                // 4 KB
    short* Wb  = (short*)(ws + 65536);               // 2 MB   [4][512][512] bf16
    short* Hn  = (short*)(ws + (4ull  << 20));       // 8 MB   [2][4096][512]
    short* QKt = (short*)(ws + (12ull << 20));       // 16 MB  [2][4096][1024]
    short* Vc  = (short*)(ws + (28ull << 20));       // 8 MB   [2][512][4096]
    short* Ot  = (short*)(ws + (36ull << 20));       // 8 MB   [2][4096][512]
    short* Sb  = (short*)(ws + (44ull << 20));       // 64 MB  [2][4096][4096] bf16

    prep<<<(4*WN + 1024 + 128 + 255)/256, 256, 0, stream>>>(wq, wk, wv, wp, bq, bk, Wb, bqk, raw);
    gn_stats<<<B_*G_*4, 256, 0, stream>>>(x, raw);
    gn_apply<<<dim3(N_/64, C_/64, B_), 256, 0, stream>>>(x, raw, gnw, gnb, Hn);

    const long long sBN = (long long)N_ * C_;
    const long long sS  = (long long)N_ * N_;

    // QK fused: [4096,1024] = Hn @ [Wq;Wk]^T + bqk   (512 blocks)
    gemm_nt<128,1,0><<<dim3(8, 32, 2), 256, 0, stream>>>(
        Hn, C_, sBN, Wb, C_, 0, QKt, 1024, (long long)N_*1024, bqk, nullptr, 1.f, C_);
    // V: [512,4096] = Wv @ Hn^T + bv   (512 blocks)
    gemm_nt<64,2,0><<<dim3(32, 8, 2), 256, 0, stream>>>(
        Wb + 2*WN, C_, 0, Hn, C_, sBN, Vc, N_, sBN, bv, nullptr, 1.f, C_);

    const float scale = 0.044194173824159216f;       // 512^-0.5
    // S = Q @ K^T * scale  -> bf16 directly, both batches (2048 blocks)
    gemm_nt<128,0,0><<<dim3(32, 32, 2), 256, 0, stream>>>(
        QKt, 1024, (long long)N_*1024, QKt + 512, 1024, (long long)N_*1024,
        Sb, N_, sS, nullptr, nullptr, scale, C_);
    // softmax rows, bf16 in place, both batches
    softmax_rows<<<B_*N_, 256, 0, stream>>>(Sb);
    // Ot = P @ Vc^T : [4096,512] bf16, BM=128 (256 blocks, 1/CU)
    gemm_nt<128,0,0><<<dim3(4, 32, 2), 256, 0, stream>>>(
        Sb, N_, sS, Vc, N_, sBN, Ot, C_, sBN, nullptr, nullptr, 1.f, N_);
    // out[b,o,n] = x + Wp @ Ot^T + bp   (512 blocks)
    gemm_nt<64,2,2><<<dim3(32, 8, 2), 256, 0, stream>>>(
        Wb + 3*WN, C_, 0, Ot, C_, sBN, out, N_, (long long)C_*N_, bp, x, 1.f, C_);
}

// Round 6
// 272.931 us; speedup vs baseline: 1.6084x; 1.0264x over previous
//
#include <hip/hip_runtime.h>
#include <hip/hip_bf16.h>
#include <stdint.h>

typedef short short8 __attribute__((ext_vector_type(8)));
typedef float f32x4  __attribute__((ext_vector_type(4)));

#define B_ 2
#define C_ 512
#define N_ 4096
#define G_ 32
#define WN (C_ * C_)

static __device__ __forceinline__ short f2bf(float f) {
    return __builtin_bit_cast(short, __float2bfloat16(f));
}
static __device__ __forceinline__ float bf2f(short s) {
    return __builtin_bit_cast(float, ((unsigned)(unsigned short)s) << 16);
}

// Barrier that does NOT drain vmcnt: only LDS ops must retire (cross-wave comm
// is LDS-only in gemm_nt). Keeps prefetched global loads in flight across the
// barrier — removes the ~900 cyc/step vmcnt(0) drain __syncthreads() causes.
// imm 0xC07F = vmcnt(63) expcnt(7) lgkmcnt(0).
static __device__ __forceinline__ void wg_barrier_lds() {
    __builtin_amdgcn_s_waitcnt(0xC07F);
    __builtin_amdgcn_s_barrier();
}

// ---- fused prep: bf16-convert 4 weights, pack bq|bk, zero gn accumulators ----
__global__ void prep(const float* __restrict__ wq, const float* __restrict__ wk,
                     const float* __restrict__ wv, const float* __restrict__ wp,
                     const float* __restrict__ bq, const float* __restrict__ bk,
                     short* __restrict__ Wb, float* __restrict__ bqk,
                     float* __restrict__ raw) {
    int i = blockIdx.x * 256 + threadIdx.x;
    if (i < 4 * WN) {
        const float* src = (i < 2*WN) ? ((i < WN) ? wq : wk) : ((i < 3*WN) ? wv : wp);
        Wb[i] = f2bf(src[i & (WN - 1)]);
    } else if (i < 4*WN + 1024) {
        int j = i - 4*WN;
        bqk[j] = (j < C_) ? bq[j] : bk[j - C_];
    } else if (i < 4*WN + 1024 + 128) {
        raw[i - (4*WN + 1024)] = 0.f;
    }
}

// ---- gn partial stats: 4 blocks per (b,g), atomicAdd raw sums ----
__global__ void gn_stats(const float* __restrict__ x, float* __restrict__ raw) {
    const int bg = blockIdx.x >> 2, qt = blockIdx.x & 3;
    const float4* p = (const float4*)(x + (size_t)bg * 16 * N_ + (size_t)qt * 4 * N_);
    int tid = threadIdx.x;
    float s = 0.f, sq = 0.f;
    #pragma unroll
    for (int rep = 0; rep < 16; rep++) {
        float4 t = p[rep * 256 + tid];
        s  += t.x + t.y + t.z + t.w;
        sq += t.x*t.x + t.y*t.y + t.z*t.z + t.w*t.w;
    }
    __shared__ float rs[256], rq[256];
    rs[tid] = s; rq[tid] = sq;
    __syncthreads();
    for (int h = 128; h > 0; h >>= 1) {
        if (tid < h) { rs[tid] += rs[tid+h]; rq[tid] += rq[tid+h]; }
        __syncthreads();
    }
    if (tid == 0) {
        atomicAdd(&raw[bg*2+0], rs[0]);
        atomicAdd(&raw[bg*2+1], rq[0]);
    }
}

// ---- groupnorm apply + transpose: x[b,c,n] fp32 -> Hn[b,n,c] bf16 ----
__global__ void gn_apply(const float* __restrict__ x, const float* __restrict__ raw,
                         const float* __restrict__ gw, const float* __restrict__ gb,
                         short* __restrict__ hn) {
    __shared__ short t[64 * 68];
    const int n0 = blockIdx.x * 64, c0 = blockIdx.y * 64, b = blockIdx.z;
    const int lane = threadIdx.x & 63, w = threadIdx.x >> 6;
    const float inv = 1.f / (16.f * N_);
    #pragma unroll
    for (int rep = 0; rep < 16; rep++) {
        int c  = rep * 4 + w;
        int cc = c0 + c;
        int g  = cc >> 4;
        float mean = raw[(b*G_ + g)*2 + 0] * inv;
        float var  = raw[(b*G_ + g)*2 + 1] * inv - mean * mean;
        float rstd = rsqrtf(var + 1e-6f);
        float sc = gw[cc] * rstd;
        float bi = gb[cc] - mean * sc;
        float v = x[((size_t)(b*C_ + cc)) * N_ + n0 + lane];
        t[lane*68 + c] = f2bf(v * sc + bi);
    }
    __syncthreads();
    #pragma unroll
    for (int rep = 0; rep < 16; rep++) {
        int n = rep * 4 + w;
        hn[((size_t)(b*N_ + n0 + n)) * C_ + c0 + lane] = t[n*68 + lane];
    }
}

// ---- generic NT GEMM, ring-4 prefetch pipeline, lgkm-only barriers ----
// C[m,n] = alpha * sum_k A[m,k]*B[n,k] (+bias) (+residual)
// Tile t: global->regs (stage t&3) at step t-3, regs->LDS (buf t&1) at step t-1,
// compute at step t. One lgkm-only barrier per step; global loads stay in flight.
// XOR-swizzled LDS (stride 32 shorts). BIAS_MODE: 0 none, 1 per-col, 2 per-row.
// OUT_MODE: 0 bf16, 1 fp32, 2 fp32+res. BM in {64,128}; BN=128; 4 waves (2x2).
// K compile-time, multiple of 128.
template<int BM, int BIAS_MODE, int OUT_MODE, int K>
__global__ __launch_bounds__(256, 2)
void gemm_nt(const short* __restrict__ A, int lda, long long sAz,
             const short* __restrict__ Bm, int ldb, long long sBz,
             void* __restrict__ Cv, int ldc, long long sCz,
             const float* __restrict__ bias,
             const float* __restrict__ res,
             float alpha) {
    constexpr int MI = BM / 32;
    constexpr int T  = K / 32;                 // #tiles, multiple of 4
    __shared__ short As[2][BM * 32];
    __shared__ short Bs[2][128 * 32];
    const int tid  = threadIdx.x;
    const int lane = tid & 63;
    const int wid  = tid >> 6;
    const int wr   = wid >> 1;
    const int wc   = wid & 1;
    const int m0 = blockIdx.y * BM;
    const int n0 = blockIdx.x * 128;
    const int z  = blockIdx.z;

    const int r   = tid >> 2;
    const int cs  = tid & 3;
    const int swo = ((cs ^ ((r >> 1) & 3)) << 3) + r * 32;

    const short* Ap  = A  + sAz * z + (long long)(m0 + r) * lda + cs * 8;
    const short* Bp  = Bm + sBz * z + (long long)(n0 + r) * ldb + cs * 8;
    const short* Ap1 = Ap + (long long)64 * lda;
    const short* Bp1 = Bp + (long long)64 * ldb;

    f32x4 acc[MI][4];
    #pragma unroll
    for (int i = 0; i < MI; i++)
        #pragma unroll
        for (int j = 0; j < 4; j++)
            acc[i][j] = f32x4{0.f, 0.f, 0.f, 0.f};

    const int fm  = lane & 15;
    const int q   = lane >> 4;
    const int swz = ((q ^ ((fm >> 1) & 3)) << 3);

    short8 ra0[4], ra1[4], rb0[4], rb1[4];     // ring of 4 register stages

    #define LOADG(s, kk) do { ra0[s] = *(const short8*)(Ap + (kk)); \
                              if (BM == 128) ra1[s] = *(const short8*)(Ap1 + (kk)); \
                              rb0[s] = *(const short8*)(Bp + (kk)); \
                              rb1[s] = *(const short8*)(Bp1 + (kk)); } while (0)
    #define STORES(b, s) do { *(short8*)&As[b][swo] = ra0[s]; \
                              if (BM == 128) *(short8*)&As[b][swo + 64*32] = ra1[s]; \
                              *(short8*)&Bs[b][swo] = rb0[s]; \
                              *(short8*)&Bs[b][swo + 64*32] = rb1[s]; } while (0)
    // step u = bt + J (bt multiple of 4, J literal 0..3)
    #define STEP(bt, J, DO_STORE, DO_LOAD) do { \
        short8 af[MI], bfr[4]; \
        _Pragma("unroll") \
        for (int i = 0; i < MI; i++) af[i] = *(const short8*)&As[(J)&1][(wr*(BM/2) + i*16 + fm)*32 + swz]; \
        _Pragma("unroll") \
        for (int i = 0; i < 4; i++)  bfr[i] = *(const short8*)&Bs[(J)&1][(wc*64 + i*16 + fm)*32 + swz]; \
        if (DO_STORE) STORES(((J)+1)&1, ((J)+1)&3); \
        if (DO_LOAD)  LOADG(((J)+3)&3, ((bt)+(J)+3)*32); \
        _Pragma("unroll") \
        for (int mi = 0; mi < MI; mi++) \
            _Pragma("unroll") \
            for (int ni = 0; ni < 4; ni++) \
                acc[mi][ni] = __builtin_amdgcn_mfma_f32_16x16x32_bf16(af[mi], bfr[ni], acc[mi][ni], 0, 0, 0); \
        wg_barrier_lds(); \
    } while (0)

    // prologue: tiles 0,1,2 into stages 0,1,2; tile0 -> LDS buf0
    LOADG(0, 0);
    LOADG(1, 32);
    LOADG(2, 64);
    STORES(0, 0);
    wg_barrier_lds();

    for (int m = 0; m < T/4 - 1; m++) {
        const int bt = m * 4;
        STEP(bt, 0, true, true);
        STEP(bt, 1, true, true);
        STEP(bt, 2, true, true);
        STEP(bt, 3, true, true);
    }
    {
        const int bt = T - 4;
        STEP(bt, 0, true,  true);    // u=T-4: store T-3, load T-1
        STEP(bt, 1, true,  false);   // u=T-3: store T-2
        STEP(bt, 2, true,  false);   // u=T-2: store T-1
        STEP(bt, 3, false, false);   // u=T-1: compute only
    }
    #undef LOADG
    #undef STORES
    #undef STEP

    const int colb = n0 + wc*64 + fm;
    const int rowb = m0 + wr*(BM/2) + (q << 2);
    #pragma unroll
    for (int mi = 0; mi < MI; mi++) {
        #pragma unroll
        for (int ni = 0; ni < 4; ni++) {
            int cc = colb + ni*16;
            float cb = (BIAS_MODE == 1) ? bias[cc] : 0.f;
            #pragma unroll
            for (int rr4 = 0; rr4 < 4; rr4++) {
                int rr = rowb + mi*16 + rr4;
                float val = acc[mi][ni][rr4] * alpha + cb;
                if (BIAS_MODE == 2) val += bias[rr];
                long long idx = sCz * z + (long long)rr * ldc + cc;
                if (OUT_MODE == 0)      ((short*)Cv)[idx] = f2bf(val);
                else if (OUT_MODE == 1) ((float*)Cv)[idx] = val;
                else                    ((float*)Cv)[idx] = val + res[idx];
            }
        }
    }
}

// ---- softmax: one wave per row, shfl reductions, no barriers ----
// grid = B_*N_/4 blocks of 256 (4 waves); bf16 in place.
__global__ void softmax_rows(short* __restrict__ S) {
    const int lane = threadIdx.x & 63;
    const int wave = threadIdx.x >> 6;
    const int row  = blockIdx.x * 4 + wave;          // 0..8191
    short8* rp = (short8*)(S + (size_t)row * N_);
    float f[64];
    float mx = -3.0e38f;
    #pragma unroll
    for (int c = 0; c < 8; c++) {
        short8 d = rp[c * 64 + lane];
        #pragma unroll
        for (int j = 0; j < 8; j++) {
            f[c*8 + j] = bf2f(d[j]);
            mx = fmaxf(mx, f[c*8 + j]);
        }
    }
    #pragma unroll
    for (int off = 32; off > 0; off >>= 1)
        mx = fmaxf(mx, __shfl_xor(mx, off));
    float sum = 0.f;
    #pragma unroll
    for (int j = 0; j < 64; j++) { f[j] = __expf(f[j] - mx); sum += f[j]; }
    #pragma unroll
    for (int off = 32; off > 0; off >>= 1)
        sum += __shfl_xor(sum, off);
    float inv = 1.f / sum;
    #pragma unroll
    for (int c = 0; c < 8; c++) {
        short8 o;
        #pragma unroll
        for (int j = 0; j < 8; j++) o[j] = f2bf(f[c*8 + j] * inv);
        rp[c * 64 + lane] = o;
    }
}

extern "C" void kernel_launch(void* const* d_in, const int* in_sizes, int n_in,
                              void* d_out, int out_size, void* d_ws, size_t ws_size,
                              hipStream_t stream) {
    const float* x   = (const float*)d_in[0];
    const float* gnw = (const float*)d_in[1];
    const float* gnb = (const float*)d_in[2];
    const float* wq  = (const float*)d_in[3];
    const float* bq  = (const float*)d_in[4];
    const float* wk  = (const float*)d_in[5];
    const float* bk  = (const float*)d_in[6];
    const float* wv  = (const float*)d_in[7];
    const float* bv  = (const float*)d_in[8];
    const float* wp  = (const float*)d_in[9];
    const float* bp  = (const float*)d_in[10];
    float* out = (float*)d_out;
    char*  ws  = (char*)d_ws;

    // workspace layout (~108 MB)
    float* raw = (float*)(ws + 0);                   // 512 B  gn accumulators
    float* bqk = (float*)(ws + 8192);                // 4 KB
    short* Wb  = (short*)(ws + 65536);               // 2 MB   [4][512][512] bf16
    short* Hn  = (short*)(ws + (4ull  << 20));       // 8 MB   [2][4096][512]
    short* QKt = (short*)(ws + (12ull << 20));       // 16 MB  [2][4096][1024]
    short* Vc  = (short*)(ws + (28ull << 20));       // 8 MB   [2][512][4096]
    short* Ot  = (short*)(ws + (36ull << 20));       // 8 MB   [2][4096][512]
    short* Sb  = (short*)(ws + (44ull << 20));       // 64 MB  [2][4096][4096] bf16

    prep<<<(4*WN + 1024 + 128 + 255)/256, 256, 0, stream>>>(wq, wk, wv, wp, bq, bk, Wb, bqk, raw);
    gn_stats<<<B_*G_*4, 256, 0, stream>>>(x, raw);
    gn_apply<<<dim3(N_/64, C_/64, B_), 256, 0, stream>>>(x, raw, gnw, gnb, Hn);

    const long long sBN = (long long)N_ * C_;
    const long long sS  = (long long)N_ * N_;

    // QK fused: [4096,1024] = Hn @ [Wq;Wk]^T + bqk   (512 blocks)
    gemm_nt<128,1,0,512><<<dim3(8, 32, 2), 256, 0, stream>>>(
        Hn, C_, sBN, Wb, C_, 0, QKt, 1024, (long long)N_*1024, bqk, nullptr, 1.f);
    // V: [512,4096] = Wv @ Hn^T + bv   (512 blocks)
    gemm_nt<64,2,0,512><<<dim3(32, 8, 2), 256, 0, stream>>>(
        Wb + 2*WN, C_, 0, Hn, C_, sBN, Vc, N_, sBN, bv, nullptr, 1.f);

    const float scale = 0.044194173824159216f;       // 512^-0.5
    // S = Q @ K^T * scale  -> bf16 directly, both batches (2048 blocks)
    gemm_nt<128,0,0,512><<<dim3(32, 32, 2), 256, 0, stream>>>(
        QKt, 1024, (long long)N_*1024, QKt + 512, 1024, (long long)N_*1024,
        Sb, N_, sS, nullptr, nullptr, scale);
    // softmax rows, one wave per row (2048 blocks)
    softmax_rows<<<B_*N_/4, 256, 0, stream>>>(Sb);
    // Ot = P @ Vc^T : [4096,512] bf16, BM=128 (256 blocks)
    gemm_nt<128,0,0,4096><<<dim3(4, 32, 2), 256, 0, stream>>>(
        Sb, N_, sS, Vc, N_, sBN, Ot, C_, sBN, nullptr, nullptr, 1.f);
    // out[b,o,n] = x + Wp @ Ot^T + bp   (512 blocks)
    gemm_nt<64,2,2,512><<<dim3(32, 8, 2), 256, 0, stream>>>(
        Wb + 3*WN, C_, 0, Ot, C_, sBN, out, N_, (long long)C_*N_, bp, x, 1.f);
}

// Round 7
// 235.831 us; speedup vs baseline: 1.8614x; 1.1573x over previous
//
#include <hip/hip_runtime.h>
#include <hip/hip_bf16.h>
#include <stdint.h>

typedef short short8 __attribute__((ext_vector_type(8)));
typedef float f32x4  __attribute__((ext_vector_type(4)));

#define B_ 2
#define C_ 512
#define N_ 4096
#define G_ 32
#define WN (C_ * C_)

static __device__ __forceinline__ short f2bf(float f) {
    return __builtin_bit_cast(short, __float2bfloat16(f));
}
static __device__ __forceinline__ float bf2f(short s) {
    return __builtin_bit_cast(float, ((unsigned)(unsigned short)s) << 16);
}
static __device__ __forceinline__ unsigned char f2fp8(float f) {
    return (unsigned char)(__builtin_amdgcn_cvt_pk_fp8_f32(f, f, 0, false) & 0xff);
}

// Barrier that does NOT drain vmcnt (cross-wave comm is LDS-only in the GEMMs).
// imm 0xC07F = vmcnt(63) expcnt(7) lgkmcnt(0).
static __device__ __forceinline__ void wg_barrier_lds() {
    __builtin_amdgcn_s_waitcnt(0xC07F);
    __builtin_amdgcn_s_barrier();
}

// ---- fused prep: bf16-convert 4 weights, pack bq|bk, zero gn accumulators ----
__global__ void prep(const float* __restrict__ wq, const float* __restrict__ wk,
                     const float* __restrict__ wv, const float* __restrict__ wp,
                     const float* __restrict__ bq, const float* __restrict__ bk,
                     short* __restrict__ Wb, float* __restrict__ bqk,
                     float* __restrict__ raw) {
    int i = blockIdx.x * 256 + threadIdx.x;
    if (i < 4 * WN) {
        const float* src = (i < 2*WN) ? ((i < WN) ? wq : wk) : ((i < 3*WN) ? wv : wp);
        Wb[i] = f2bf(src[i & (WN - 1)]);
    } else if (i < 4*WN + 1024) {
        int j = i - 4*WN;
        bqk[j] = (j < C_) ? bq[j] : bk[j - C_];
    } else if (i < 4*WN + 1024 + 128) {
        raw[i - (4*WN + 1024)] = 0.f;
    }
}

// ---- gn partial stats: 4 blocks per (b,g), atomicAdd raw sums ----
__global__ void gn_stats(const float* __restrict__ x, float* __restrict__ raw) {
    const int bg = blockIdx.x >> 2, qt = blockIdx.x & 3;
    const float4* p = (const float4*)(x + (size_t)bg * 16 * N_ + (size_t)qt * 4 * N_);
    int tid = threadIdx.x;
    float s = 0.f, sq = 0.f;
    #pragma unroll
    for (int rep = 0; rep < 16; rep++) {
        float4 t = p[rep * 256 + tid];
        s  += t.x + t.y + t.z + t.w;
        sq += t.x*t.x + t.y*t.y + t.z*t.z + t.w*t.w;
    }
    __shared__ float rs[256], rq[256];
    rs[tid] = s; rq[tid] = sq;
    __syncthreads();
    for (int h = 128; h > 0; h >>= 1) {
        if (tid < h) { rs[tid] += rs[tid+h]; rq[tid] += rq[tid+h]; }
        __syncthreads();
    }
    if (tid == 0) {
        atomicAdd(&raw[bg*2+0], rs[0]);
        atomicAdd(&raw[bg*2+1], rq[0]);
    }
}

// ---- groupnorm apply + transpose: x[b,c,n] fp32 -> Hn[b,n,c] bf16 ----
__global__ void gn_apply(const float* __restrict__ x, const float* __restrict__ raw,
                         const float* __restrict__ gw, const float* __restrict__ gb,
                         short* __restrict__ hn) {
    __shared__ short t[64 * 68];
    const int n0 = blockIdx.x * 64, c0 = blockIdx.y * 64, b = blockIdx.z;
    const int lane = threadIdx.x & 63, w = threadIdx.x >> 6;
    const float inv = 1.f / (16.f * N_);
    #pragma unroll
    for (int rep = 0; rep < 16; rep++) {
        int c  = rep * 4 + w;
        int cc = c0 + c;
        int g  = cc >> 4;
        float mean = raw[(b*G_ + g)*2 + 0] * inv;
        float var  = raw[(b*G_ + g)*2 + 1] * inv - mean * mean;
        float rstd = rsqrtf(var + 1e-6f);
        float sc = gw[cc] * rstd;
        float bi = gb[cc] - mean * sc;
        float v = x[((size_t)(b*C_ + cc)) * N_ + n0 + lane];
        t[lane*68 + c] = f2bf(v * sc + bi);
    }
    __syncthreads();
    #pragma unroll
    for (int rep = 0; rep < 16; rep++) {
        int n = rep * 4 + w;
        hn[((size_t)(b*N_ + n0 + n)) * C_ + c0 + lane] = t[n*68 + lane];
    }
}

// ---- generic NT GEMM (bf16), ring-4 prefetch, lgkm-only barriers ----
// BIAS_MODE: 0 none, 1 per-col, 2 per-row.
// OUT_MODE: 0 bf16, 1 fp32, 2 fp32+res, 3 fp8(e4m3).
template<int BM, int BIAS_MODE, int OUT_MODE, int K>
__global__ __launch_bounds__(256, 2)
void gemm_nt(const short* __restrict__ A, int lda, long long sAz,
             const short* __restrict__ Bm, int ldb, long long sBz,
             void* __restrict__ Cv, int ldc, long long sCz,
             const float* __restrict__ bias,
             const float* __restrict__ res,
             float alpha) {
    constexpr int MI = BM / 32;
    constexpr int T  = K / 32;
    __shared__ short As[2][BM * 32];
    __shared__ short Bs[2][128 * 32];
    const int tid  = threadIdx.x;
    const int lane = tid & 63;
    const int wid  = tid >> 6;
    const int wr   = wid >> 1;
    const int wc   = wid & 1;
    const int m0 = blockIdx.y * BM;
    const int n0 = blockIdx.x * 128;
    const int z  = blockIdx.z;

    const int r   = tid >> 2;
    const int cs  = tid & 3;
    const int swo = ((cs ^ ((r >> 1) & 3)) << 3) + r * 32;

    const short* Ap  = A  + sAz * z + (long long)(m0 + r) * lda + cs * 8;
    const short* Bp  = Bm + sBz * z + (long long)(n0 + r) * ldb + cs * 8;
    const short* Ap1 = Ap + (long long)64 * lda;
    const short* Bp1 = Bp + (long long)64 * ldb;

    f32x4 acc[MI][4];
    #pragma unroll
    for (int i = 0; i < MI; i++)
        #pragma unroll
        for (int j = 0; j < 4; j++)
            acc[i][j] = f32x4{0.f, 0.f, 0.f, 0.f};

    const int fm  = lane & 15;
    const int q   = lane >> 4;
    const int swz = ((q ^ ((fm >> 1) & 3)) << 3);

    short8 ra0[4], ra1[4], rb0[4], rb1[4];

    #define LOADG(s, kk) do { ra0[s] = *(const short8*)(Ap + (kk)); \
                              if (BM == 128) ra1[s] = *(const short8*)(Ap1 + (kk)); \
                              rb0[s] = *(const short8*)(Bp + (kk)); \
                              rb1[s] = *(const short8*)(Bp1 + (kk)); } while (0)
    #define STORES(b, s) do { *(short8*)&As[b][swo] = ra0[s]; \
                              if (BM == 128) *(short8*)&As[b][swo + 64*32] = ra1[s]; \
                              *(short8*)&Bs[b][swo] = rb0[s]; \
                              *(short8*)&Bs[b][swo + 64*32] = rb1[s]; } while (0)
    #define STEP(bt, J, DO_STORE, DO_LOAD) do { \
        short8 af[MI], bfr[4]; \
        _Pragma("unroll") \
        for (int i = 0; i < MI; i++) af[i] = *(const short8*)&As[(J)&1][(wr*(BM/2) + i*16 + fm)*32 + swz]; \
        _Pragma("unroll") \
        for (int i = 0; i < 4; i++)  bfr[i] = *(const short8*)&Bs[(J)&1][(wc*64 + i*16 + fm)*32 + swz]; \
        if (DO_STORE) STORES(((J)+1)&1, ((J)+1)&3); \
        if (DO_LOAD)  LOADG(((J)+3)&3, ((bt)+(J)+3)*32); \
        _Pragma("unroll") \
        for (int mi = 0; mi < MI; mi++) \
            _Pragma("unroll") \
            for (int ni = 0; ni < 4; ni++) \
                acc[mi][ni] = __builtin_amdgcn_mfma_f32_16x16x32_bf16(af[mi], bfr[ni], acc[mi][ni], 0, 0, 0); \
        wg_barrier_lds(); \
    } while (0)

    LOADG(0, 0);
    LOADG(1, 32);
    LOADG(2, 64);
    STORES(0, 0);
    wg_barrier_lds();

    for (int m = 0; m < T/4 - 1; m++) {
        const int bt = m * 4;
        STEP(bt, 0, true, true);
        STEP(bt, 1, true, true);
        STEP(bt, 2, true, true);
        STEP(bt, 3, true, true);
    }
    {
        const int bt = T - 4;
        STEP(bt, 0, true,  true);
        STEP(bt, 1, true,  false);
        STEP(bt, 2, true,  false);
        STEP(bt, 3, false, false);
    }
    #undef LOADG
    #undef STORES
    #undef STEP

    const int colb = n0 + wc*64 + fm;
    const int rowb = m0 + wr*(BM/2) + (q << 2);
    #pragma unroll
    for (int mi = 0; mi < MI; mi++) {
        #pragma unroll
        for (int ni = 0; ni < 4; ni++) {
            int cc = colb + ni*16;
            float cb = (BIAS_MODE == 1) ? bias[cc] : 0.f;
            #pragma unroll
            for (int rr4 = 0; rr4 < 4; rr4++) {
                int rr = rowb + mi*16 + rr4;
                float val = acc[mi][ni][rr4] * alpha + cb;
                if (BIAS_MODE == 2) val += bias[rr];
                long long idx = sCz * z + (long long)rr * ldc + cc;
                if (OUT_MODE == 0)      ((short*)Cv)[idx] = f2bf(val);
                else if (OUT_MODE == 1) ((float*)Cv)[idx] = val;
                else if (OUT_MODE == 2) ((float*)Cv)[idx] = val + res[idx];
                else                    ((unsigned char*)Cv)[idx] = f2fp8(val);
            }
        }
    }
}

// ---- fp8 PV GEMM: Ot[i,c] = (1/256) * sum_j P8[i,j] V8[c,j] ----
// BM=BN=128, BK=64, K=4096 (64 steps). P8 rows at 8192-byte stride.
// LDS: 64 B/row, 8B-granule XOR swizzle (slot = k8 ^ (row&7)); writer stores
// 16B chunks at block c^((r>>1)&3) with halves swapped iff r&1. 2-way max (free).
__global__ __launch_bounds__(256, 2)
void gemm_pv_fp8(const unsigned char* __restrict__ P, const unsigned char* __restrict__ V,
                 short* __restrict__ Ot, float oscale) {
    __shared__ unsigned char As[2][128 * 64];
    __shared__ unsigned char Bs[2][128 * 64];
    const int tid  = threadIdx.x;
    const int lane = tid & 63;
    const int wid  = tid >> 6;
    const int wr   = wid >> 1;
    const int wc   = wid & 1;
    const int m0 = blockIdx.y * 128;
    const int n0 = blockIdx.x * 128;
    const int z  = blockIdx.z;

    const int r = tid >> 2;              // 0..63 (also handles r+64)
    const int c = tid & 3;               // 16B chunk within 64B row
    const int wofs = r * 64 + ((c ^ ((r >> 1) & 3)) << 4);
    const bool swp = (r & 1) != 0;

    const unsigned char* Ap  = P + (size_t)z * N_ * 8192 + (size_t)(m0 + r) * 8192 + c * 16;
    const unsigned char* Ap1 = Ap + (size_t)64 * 8192;
    const unsigned char* Bp  = V + (size_t)z * C_ * N_ + (size_t)(n0 + r) * N_ + c * 16;
    const unsigned char* Bp1 = Bp + (size_t)64 * N_;

    f32x4 acc[4][4];
    #pragma unroll
    for (int i = 0; i < 4; i++)
        #pragma unroll
        for (int j = 0; j < 4; j++)
            acc[i][j] = f32x4{0.f, 0.f, 0.f, 0.f};

    const int fm = lane & 15;
    const int q  = lane >> 4;
    const int e  = fm & 7;
    const int ro0 = ((q ^ e) << 3);          // k-group 0 byte offset in row
    const int ro1 = (((4 + q) ^ e) << 3);    // k-group 1

    short8 ra[4][2], rb[4][2];

    #define ST16(dst, v) do { short8 _w; \
        if (swp) { _w[0]=(v)[4];_w[1]=(v)[5];_w[2]=(v)[6];_w[3]=(v)[7]; \
                   _w[4]=(v)[0];_w[5]=(v)[1];_w[6]=(v)[2];_w[7]=(v)[3]; } \
        else _w = (v); \
        *(short8*)(dst) = _w; } while (0)
    #define LOADG(s, kb) do { ra[s][0] = *(const short8*)(Ap  + (kb)); \
                              ra[s][1] = *(const short8*)(Ap1 + (kb)); \
                              rb[s][0] = *(const short8*)(Bp  + (kb)); \
                              rb[s][1] = *(const short8*)(Bp1 + (kb)); } while (0)
    #define STORES(b, s) do { ST16(&As[b][wofs], ra[s][0]); ST16(&As[b][wofs + 64*64], ra[s][1]); \
                              ST16(&Bs[b][wofs], rb[s][0]); ST16(&Bs[b][wofs + 64*64], rb[s][1]); } while (0)
    #define STEP(bt, J, DO_STORE, DO_LOAD) do { \
        long af0[4], af1[4], bf0[4], bf1[4]; \
        _Pragma("unroll") \
        for (int i = 0; i < 4; i++) { \
            int ar = (wr*64 + i*16 + fm) * 64; \
            int br = (wc*64 + i*16 + fm) * 64; \
            af0[i] = *(const long*)&As[(J)&1][ar + ro0]; \
            af1[i] = *(const long*)&As[(J)&1][ar + ro1]; \
            bf0[i] = *(const long*)&Bs[(J)&1][br + ro0]; \
            bf1[i] = *(const long*)&Bs[(J)&1][br + ro1]; \
        } \
        if (DO_STORE) STORES(((J)+1)&1, ((J)+1)&3); \
        if (DO_LOAD)  LOADG(((J)+3)&3, ((bt)+(J)+3)*64); \
        _Pragma("unroll") \
        for (int mi = 0; mi < 4; mi++) \
            _Pragma("unroll") \
            for (int ni = 0; ni < 4; ni++) \
                acc[mi][ni] = __builtin_amdgcn_mfma_f32_16x16x32_fp8_fp8(af0[mi], bf0[ni], acc[mi][ni], 0, 0, 0); \
        _Pragma("unroll") \
        for (int mi = 0; mi < 4; mi++) \
            _Pragma("unroll") \
            for (int ni = 0; ni < 4; ni++) \
                acc[mi][ni] = __builtin_amdgcn_mfma_f32_16x16x32_fp8_fp8(af1[mi], bf1[ni], acc[mi][ni], 0, 0, 0); \
        wg_barrier_lds(); \
    } while (0)

    LOADG(0, 0);
    LOADG(1, 64);
    LOADG(2, 128);
    STORES(0, 0);
    wg_barrier_lds();

    for (int m = 0; m < 15; m++) {           // T=64 steps of BK=64
        const int bt = m * 4;
        STEP(bt, 0, true, true);
        STEP(bt, 1, true, true);
        STEP(bt, 2, true, true);
        STEP(bt, 3, true, true);
    }
    {
        const int bt = 60;
        STEP(bt, 0, true,  true);
        STEP(bt, 1, true,  false);
        STEP(bt, 2, true,  false);
        STEP(bt, 3, false, false);
    }
    #undef ST16
    #undef LOADG
    #undef STORES
    #undef STEP

    const int colb = n0 + wc*64 + fm;
    const int rowb = m0 + wr*64 + (q << 2);
    #pragma unroll
    for (int mi = 0; mi < 4; mi++) {
        #pragma unroll
        for (int ni = 0; ni < 4; ni++) {
            int cc = colb + ni*16;
            #pragma unroll
            for (int rr4 = 0; rr4 < 4; rr4++) {
                int rr = rowb + mi*16 + rr4;
                Ot[(long long)z * N_ * C_ + (long long)rr * C_ + cc] = f2bf(acc[mi][ni][rr4] * oscale);
            }
        }
    }
}

// ---- softmax: one wave per row; bf16 in, fp8(x256) out in place at row head ----
__global__ void softmax_rows(short* __restrict__ S) {
    const int lane = threadIdx.x & 63;
    const int wave = threadIdx.x >> 6;
    const int row  = blockIdx.x * 4 + wave;          // 0..8191
    short8* rp = (short8*)(S + (size_t)row * N_);
    float f[64];
    float mx = -3.0e38f;
    #pragma unroll
    for (int c = 0; c < 8; c++) {
        short8 d = rp[c * 64 + lane];
        #pragma unroll
        for (int j = 0; j < 8; j++) {
            f[c*8 + j] = bf2f(d[j]);
            mx = fmaxf(mx, f[c*8 + j]);
        }
    }
    #pragma unroll
    for (int off = 32; off > 0; off >>= 1)
        mx = fmaxf(mx, __shfl_xor(mx, off));
    float sum = 0.f;
    #pragma unroll
    for (int j = 0; j < 64; j++) { f[j] = __expf(f[j] - mx); sum += f[j]; }
    #pragma unroll
    for (int off = 32; off > 0; off >>= 1)
        sum += __shfl_xor(sum, off);
    float inv = 256.f / sum;                         // store P*256 in fp8
    unsigned char* ob = (unsigned char*)(S + (size_t)row * N_);
    #pragma unroll
    for (int c = 0; c < 8; c++) {
        int lo = 0, hi = 0;
        lo = __builtin_amdgcn_cvt_pk_fp8_f32(f[c*8+0]*inv, f[c*8+1]*inv, lo, false);
        lo = __builtin_amdgcn_cvt_pk_fp8_f32(f[c*8+2]*inv, f[c*8+3]*inv, lo, true);
        hi = __builtin_amdgcn_cvt_pk_fp8_f32(f[c*8+4]*inv, f[c*8+5]*inv, hi, false);
        hi = __builtin_amdgcn_cvt_pk_fp8_f32(f[c*8+6]*inv, f[c*8+7]*inv, hi, true);
        unsigned long long o = ((unsigned long long)(unsigned)hi << 32) | (unsigned)lo;
        *(unsigned long long*)&ob[(size_t)(c * 64 + lane) * 8] = o;
    }
}

extern "C" void kernel_launch(void* const* d_in, const int* in_sizes, int n_in,
                              void* d_out, int out_size, void* d_ws, size_t ws_size,
                              hipStream_t stream) {
    const float* x   = (const float*)d_in[0];
    const float* gnw = (const float*)d_in[1];
    const float* gnb = (const float*)d_in[2];
    const float* wq  = (const float*)d_in[3];
    const float* bq  = (const float*)d_in[4];
    const float* wk  = (const float*)d_in[5];
    const float* bk  = (const float*)d_in[6];
    const float* wv  = (const float*)d_in[7];
    const float* bv  = (const float*)d_in[8];
    const float* wp  = (const float*)d_in[9];
    const float* bp  = (const float*)d_in[10];
    float* out = (float*)d_out;
    char*  ws  = (char*)d_ws;

    // workspace layout (~108 MB)
    float* raw = (float*)(ws + 0);                   // 512 B
    float* bqk = (float*)(ws + 8192);                // 4 KB
    short* Wb  = (short*)(ws + 65536);               // 2 MB   [4][512][512] bf16
    short* Hn  = (short*)(ws + (4ull  << 20));       // 8 MB   [2][4096][512]
    short* QKt = (short*)(ws + (12ull << 20));       // 16 MB  [2][4096][1024]
    unsigned char* Vc = (unsigned char*)(ws + (28ull << 20)); // 4 MB [2][512][4096] fp8
    short* Ot  = (short*)(ws + (36ull << 20));       // 8 MB   [2][4096][512]
    short* Sb  = (short*)(ws + (44ull << 20));       // 64 MB  [2][4096][4096] bf16 (P fp8 in place)

    prep<<<(4*WN + 1024 + 128 + 255)/256, 256, 0, stream>>>(wq, wk, wv, wp, bq, bk, Wb, bqk, raw);
    gn_stats<<<B_*G_*4, 256, 0, stream>>>(x, raw);
    gn_apply<<<dim3(N_/64, C_/64, B_), 256, 0, stream>>>(x, raw, gnw, gnb, Hn);

    const long long sBN = (long long)N_ * C_;
    const long long sS  = (long long)N_ * N_;

    // QK fused: [4096,1024] = Hn @ [Wq;Wk]^T + bqk   (512 blocks)
    gemm_nt<128,1,0,512><<<dim3(8, 32, 2), 256, 0, stream>>>(
        Hn, C_, sBN, Wb, C_, 0, QKt, 1024, (long long)N_*1024, bqk, nullptr, 1.f);
    // V: [512,4096] fp8 = Wv @ Hn^T + bv   (512 blocks)
    gemm_nt<64,2,3,512><<<dim3(32, 8, 2), 256, 0, stream>>>(
        Wb + 2*WN, C_, 0, Hn, C_, sBN, Vc, N_, sBN, bv, nullptr, 1.f);

    const float scale = 0.044194173824159216f;       // 512^-0.5
    // S = Q @ K^T * scale  -> bf16, both batches (2048 blocks)
    gemm_nt<128,0,0,512><<<dim3(32, 32, 2), 256, 0, stream>>>(
        QKt, 1024, (long long)N_*1024, QKt + 512, 1024, (long long)N_*1024,
        Sb, N_, sS, nullptr, nullptr, scale);
    // softmax rows -> fp8 P*256 in place (2048 blocks)
    softmax_rows<<<B_*N_/4, 256, 0, stream>>>(Sb);
    // Ot = (P8 @ V8^T)/256 : [4096,512] bf16 (256 blocks)
    gemm_pv_fp8<<<dim3(4, 32, 2), 256, 0, stream>>>(
        (const unsigned char*)Sb, Vc, Ot, 1.f/256.f);
    // out[b,o,n] = x + Wp @ Ot^T + bp   (512 blocks)
    gemm_nt<64,2,2,512><<<dim3(32, 8, 2), 256, 0, stream>>>(
        Wb + 3*WN, C_, 0, Ot, C_, sBN, out, N_, (long long)C_*N_, bp, x, 1.f);
}

// Round 8
// 224.744 us; speedup vs baseline: 1.9532x; 1.0493x over previous
//
#include <hip/hip_runtime.h>
#include <hip/hip_bf16.h>
#include <stdint.h>

typedef short short8 __attribute__((ext_vector_type(8)));
typedef float f32x4  __attribute__((ext_vector_type(4)));
typedef unsigned char uchar;

#define B_ 2
#define C_ 512
#define N_ 4096
#define G_ 32
#define WN (C_ * C_)

static __device__ __forceinline__ short f2bf(float f) {
    return __builtin_bit_cast(short, __float2bfloat16(f));
}
static __device__ __forceinline__ float bf2f(short s) {
    return __builtin_bit_cast(float, ((unsigned)(unsigned short)s) << 16);
}
static __device__ __forceinline__ uchar f2fp8(float f) {
    return (uchar)(__builtin_amdgcn_cvt_pk_fp8_f32(f, f, 0, false) & 0xff);
}

// Barrier that does NOT drain vmcnt (cross-wave comm is LDS-only in the GEMMs).
// imm 0xC07F = vmcnt(63) expcnt(7) lgkmcnt(0).
static __device__ __forceinline__ void wg_barrier_lds() {
    __builtin_amdgcn_s_waitcnt(0xC07F);
    __builtin_amdgcn_s_barrier();
}

// ---- fused prep: fp8-convert 4 weights (x16 prescale), pack bq|bk, zero gn acc ----
__global__ void prep(const float* __restrict__ wq, const float* __restrict__ wk,
                     const float* __restrict__ wv, const float* __restrict__ wp,
                     const float* __restrict__ bq, const float* __restrict__ bk,
                     uchar* __restrict__ Wb, float* __restrict__ bqk,
                     float* __restrict__ raw) {
    int i = blockIdx.x * 256 + threadIdx.x;
    if (i < 4 * WN) {
        const float* src = (i < 2*WN) ? ((i < WN) ? wq : wk) : ((i < 3*WN) ? wv : wp);
        Wb[i] = f2fp8(src[i & (WN - 1)] * 16.f);
    } else if (i < 4*WN + 1024) {
        int j = i - 4*WN;
        bqk[j] = (j < C_) ? bq[j] : bk[j - C_];
    } else if (i < 4*WN + 1024 + 128) {
        raw[i - (4*WN + 1024)] = 0.f;
    }
}

// ---- gn partial stats: 4 blocks per (b,g), atomicAdd raw sums ----
__global__ void gn_stats(const float* __restrict__ x, float* __restrict__ raw) {
    const int bg = blockIdx.x >> 2, qt = blockIdx.x & 3;
    const float4* p = (const float4*)(x + (size_t)bg * 16 * N_ + (size_t)qt * 4 * N_);
    int tid = threadIdx.x;
    float s = 0.f, sq = 0.f;
    #pragma unroll
    for (int rep = 0; rep < 16; rep++) {
        float4 t = p[rep * 256 + tid];
        s  += t.x + t.y + t.z + t.w;
        sq += t.x*t.x + t.y*t.y + t.z*t.z + t.w*t.w;
    }
    __shared__ float rs[256], rq[256];
    rs[tid] = s; rq[tid] = sq;
    __syncthreads();
    for (int h = 128; h > 0; h >>= 1) {
        if (tid < h) { rs[tid] += rs[tid+h]; rq[tid] += rq[tid+h]; }
        __syncthreads();
    }
    if (tid == 0) {
        atomicAdd(&raw[bg*2+0], rs[0]);
        atomicAdd(&raw[bg*2+1], rq[0]);
    }
}

// ---- groupnorm apply + transpose: x[b,c,n] fp32 -> Hn[b,n,c] fp8 ----
__global__ void gn_apply(const float* __restrict__ x, const float* __restrict__ raw,
                         const float* __restrict__ gw, const float* __restrict__ gb,
                         uchar* __restrict__ hn) {
    __shared__ uchar t[64 * 68];
    const int n0 = blockIdx.x * 64, c0 = blockIdx.y * 64, b = blockIdx.z;
    const int lane = threadIdx.x & 63, w = threadIdx.x >> 6;
    const float inv = 1.f / (16.f * N_);
    #pragma unroll
    for (int rep = 0; rep < 16; rep++) {
        int c  = rep * 4 + w;
        int cc = c0 + c;
        int g  = cc >> 4;
        float mean = raw[(b*G_ + g)*2 + 0] * inv;
        float var  = raw[(b*G_ + g)*2 + 1] * inv - mean * mean;
        float rstd = rsqrtf(var + 1e-6f);
        float sc = gw[cc] * rstd;
        float bi = gb[cc] - mean * sc;
        float v = x[((size_t)(b*C_ + cc)) * N_ + n0 + lane];
        t[lane*68 + c] = f2fp8(v * sc + bi);
    }
    __syncthreads();
    #pragma unroll
    for (int rep = 0; rep < 16; rep++) {
        int n = rep * 4 + w;
        hn[((size_t)(b*N_ + n0 + n)) * C_ + c0 + lane] = t[n*68 + lane];
    }
}

// ---- generic fp8 NT GEMM, ring-4 prefetch, lgkm-only barriers ----
// C[m,n] = alpha * sum_k A[m,k]*B[n,k] (+bias) (+residual)
// A,B fp8 e4m3; lda/ldb/sAz/sBz in BYTES; ldc/sCz in elements.
// BK=64 (one 64-byte LDS row per matrix row). 8B-granule XOR swizzle:
// writer puts 16B chunk c at slot c^((r>>1)&3), halves swapped iff r&1;
// reader offset ((q^e)<<3) / (((4+q)^e)<<3), e=fm&7.  (verified round 7)
// BIAS_MODE: 0 none, 1 per-col, 2 per-row. OUT_MODE: 0 bf16, 2 fp32+res, 3 fp8.
// BM in {64,128}; BN=128; 4 waves (2x2). K multiple of 256.
template<int BM, int BIAS_MODE, int OUT_MODE, int K>
__global__ __launch_bounds__(256, 2)
void gemm_nt8(const uchar* __restrict__ A, int lda, long long sAz,
              const uchar* __restrict__ Bm, int ldb, long long sBz,
              void* __restrict__ Cv, int ldc, long long sCz,
              const float* __restrict__ bias,
              const float* __restrict__ res,
              float alpha) {
    constexpr int MI = BM / 32;
    constexpr int T  = K / 64;
    __shared__ uchar As[2][BM * 64];
    __shared__ uchar Bs[2][128 * 64];
    const int tid  = threadIdx.x;
    const int lane = tid & 63;
    const int wid  = tid >> 6;
    const int wr   = wid >> 1;
    const int wc   = wid & 1;
    const int m0 = blockIdx.y * BM;
    const int n0 = blockIdx.x * 128;
    const int z  = blockIdx.z;

    const int r = tid >> 2;                  // 0..63
    const int c = tid & 3;                   // 16B chunk in 64B row
    const int wofs = r * 64 + ((c ^ ((r >> 1) & 3)) << 4);
    const bool swp = (r & 1) != 0;

    const uchar* Ap  = A  + sAz * z + (size_t)(m0 + r) * lda + c * 16;
    const uchar* Ap1 = Ap + (size_t)64 * lda;
    const uchar* Bp  = Bm + sBz * z + (size_t)(n0 + r) * ldb + c * 16;
    const uchar* Bp1 = Bp + (size_t)64 * ldb;

    f32x4 acc[MI][4];
    #pragma unroll
    for (int i = 0; i < MI; i++)
        #pragma unroll
        for (int j = 0; j < 4; j++)
            acc[i][j] = f32x4{0.f, 0.f, 0.f, 0.f};

    const int fm = lane & 15;
    const int q  = lane >> 4;
    const int e  = fm & 7;
    const int ro0 = ((q ^ e) << 3);
    const int ro1 = (((4 + q) ^ e) << 3);

    short8 ra[4][2], rb[4][2];

    #define ST16(dst, v) do { short8 _w; \
        if (swp) { _w[0]=(v)[4];_w[1]=(v)[5];_w[2]=(v)[6];_w[3]=(v)[7]; \
                   _w[4]=(v)[0];_w[5]=(v)[1];_w[6]=(v)[2];_w[7]=(v)[3]; } \
        else _w = (v); \
        *(short8*)(dst) = _w; } while (0)
    #define LOADG(s, kb) do { ra[s][0] = *(const short8*)(Ap  + (kb)); \
                              if (BM == 128) ra[s][1] = *(const short8*)(Ap1 + (kb)); \
                              rb[s][0] = *(const short8*)(Bp  + (kb)); \
                              rb[s][1] = *(const short8*)(Bp1 + (kb)); } while (0)
    #define STORES(b, s) do { ST16(&As[b][wofs], ra[s][0]); \
                              if (BM == 128) ST16(&As[b][wofs + 64*64], ra[s][1]); \
                              ST16(&Bs[b][wofs], rb[s][0]); ST16(&Bs[b][wofs + 64*64], rb[s][1]); } while (0)
    #define STEP(bt, J, DO_STORE, DO_LOAD) do { \
        long af0[MI], af1[MI], bf0[4], bf1[4]; \
        _Pragma("unroll") \
        for (int i = 0; i < MI; i++) { \
            int ar = (wr*(BM/2) + i*16 + fm) * 64; \
            af0[i] = *(const long*)&As[(J)&1][ar + ro0]; \
            af1[i] = *(const long*)&As[(J)&1][ar + ro1]; \
        } \
        _Pragma("unroll") \
        for (int i = 0; i < 4; i++) { \
            int br = (wc*64 + i*16 + fm) * 64; \
            bf0[i] = *(const long*)&Bs[(J)&1][br + ro0]; \
            bf1[i] = *(const long*)&Bs[(J)&1][br + ro1]; \
        } \
        if (DO_STORE) STORES(((J)+1)&1, ((J)+1)&3); \
        if (DO_LOAD)  LOADG(((J)+3)&3, ((bt)+(J)+3)*64); \
        _Pragma("unroll") \
        for (int mi = 0; mi < MI; mi++) \
            _Pragma("unroll") \
            for (int ni = 0; ni < 4; ni++) \
                acc[mi][ni] = __builtin_amdgcn_mfma_f32_16x16x32_fp8_fp8(af0[mi], bf0[ni], acc[mi][ni], 0, 0, 0); \
        _Pragma("unroll") \
        for (int mi = 0; mi < MI; mi++) \
            _Pragma("unroll") \
            for (int ni = 0; ni < 4; ni++) \
                acc[mi][ni] = __builtin_amdgcn_mfma_f32_16x16x32_fp8_fp8(af1[mi], bf1[ni], acc[mi][ni], 0, 0, 0); \
        wg_barrier_lds(); \
    } while (0)

    LOADG(0, 0);
    LOADG(1, 64);
    LOADG(2, 128);
    STORES(0, 0);
    wg_barrier_lds();

    for (int m = 0; m < T/4 - 1; m++) {
        const int bt = m * 4;
        STEP(bt, 0, true, true);
        STEP(bt, 1, true, true);
        STEP(bt, 2, true, true);
        STEP(bt, 3, true, true);
    }
    {
        const int bt = T - 4;
        STEP(bt, 0, true,  true);
        STEP(bt, 1, true,  false);
        STEP(bt, 2, true,  false);
        STEP(bt, 3, false, false);
    }
    #undef ST16
    #undef LOADG
    #undef STORES
    #undef STEP

    const int colb = n0 + wc*64 + fm;
    const int rowb = m0 + wr*(BM/2) + (q << 2);
    #pragma unroll
    for (int mi = 0; mi < MI; mi++) {
        #pragma unroll
        for (int ni = 0; ni < 4; ni++) {
            int cc = colb + ni*16;
            float cb = (BIAS_MODE == 1) ? bias[cc] : 0.f;
            #pragma unroll
            for (int rr4 = 0; rr4 < 4; rr4++) {
                int rr = rowb + mi*16 + rr4;
                float val = acc[mi][ni][rr4] * alpha + cb;
                if (BIAS_MODE == 2) val += bias[rr];
                long long idx = sCz * z + (long long)rr * ldc + cc;
                if (OUT_MODE == 0)      ((short*)Cv)[idx] = f2bf(val);
                else if (OUT_MODE == 2) ((float*)Cv)[idx] = val + res[idx];
                else                    ((uchar*)Cv)[idx] = f2fp8(val);
            }
        }
    }
}

// ---- softmax: one wave per row; bf16 in, fp8(x256) out in place at row head ----
__global__ void softmax_rows(short* __restrict__ S) {
    const int lane = threadIdx.x & 63;
    const int wave = threadIdx.x >> 6;
    const int row  = blockIdx.x * 4 + wave;          // 0..8191
    short8* rp = (short8*)(S + (size_t)row * N_);
    float f[64];
    float mx = -3.0e38f;
    #pragma unroll
    for (int c = 0; c < 8; c++) {
        short8 d = rp[c * 64 + lane];
        #pragma unroll
        for (int j = 0; j < 8; j++) {
            f[c*8 + j] = bf2f(d[j]);
            mx = fmaxf(mx, f[c*8 + j]);
        }
    }
    #pragma unroll
    for (int off = 32; off > 0; off >>= 1)
        mx = fmaxf(mx, __shfl_xor(mx, off));
    float sum = 0.f;
    #pragma unroll
    for (int j = 0; j < 64; j++) { f[j] = __expf(f[j] - mx); sum += f[j]; }
    #pragma unroll
    for (int off = 32; off > 0; off >>= 1)
        sum += __shfl_xor(sum, off);
    float inv = 256.f / sum;                         // store P*256 in fp8
    uchar* ob = (uchar*)(S + (size_t)row * N_);
    #pragma unroll
    for (int c = 0; c < 8; c++) {
        int lo = 0, hi = 0;
        lo = __builtin_amdgcn_cvt_pk_fp8_f32(f[c*8+0]*inv, f[c*8+1]*inv, lo, false);
        lo = __builtin_amdgcn_cvt_pk_fp8_f32(f[c*8+2]*inv, f[c*8+3]*inv, lo, true);
        hi = __builtin_amdgcn_cvt_pk_fp8_f32(f[c*8+4]*inv, f[c*8+5]*inv, hi, false);
        hi = __builtin_amdgcn_cvt_pk_fp8_f32(f[c*8+6]*inv, f[c*8+7]*inv, hi, true);
        unsigned long long o = ((unsigned long long)(unsigned)hi << 32) | (unsigned)lo;
        *(unsigned long long*)&ob[(size_t)(c * 64 + lane) * 8] = o;
    }
}

extern "C" void kernel_launch(void* const* d_in, const int* in_sizes, int n_in,
                              void* d_out, int out_size, void* d_ws, size_t ws_size,
                              hipStream_t stream) {
    const float* x   = (const float*)d_in[0];
    const float* gnw = (const float*)d_in[1];
    const float* gnb = (const float*)d_in[2];
    const float* wq  = (const float*)d_in[3];
    const float* bq  = (const float*)d_in[4];
    const float* wk  = (const float*)d_in[5];
    const float* bk  = (const float*)d_in[6];
    const float* wv  = (const float*)d_in[7];
    const float* bv  = (const float*)d_in[8];
    const float* wp  = (const float*)d_in[9];
    const float* bp  = (const float*)d_in[10];
    float* out = (float*)d_out;
    char*  ws  = (char*)d_ws;

    // workspace layout (~88 MB)
    float* raw = (float*)(ws + 0);                   // 512 B
    float* bqk = (float*)(ws + 8192);                // 4 KB
    uchar* Wb  = (uchar*)(ws + 65536);               // 1 MB  [4][512][512] fp8 (x16)
    uchar* Hn  = (uchar*)(ws + (2ull  << 20));       // 4 MB  [2][4096][512] fp8
    uchar* QK8 = (uchar*)(ws + (8ull  << 20));       // 8 MB  [2][4096][1024] fp8 (Q|K)
    uchar* V8  = (uchar*)(ws + (16ull << 20));       // 4 MB  [2][512][4096] fp8
    uchar* Ot8 = (uchar*)(ws + (20ull << 20));       // 4 MB  [2][4096][512] fp8 (x16)
    short* Sb  = (short*)(ws + (24ull << 20));       // 64 MB [2][4096][4096] bf16 (P fp8 in place)

    prep<<<(4*WN + 1024 + 128 + 255)/256, 256, 0, stream>>>(wq, wk, wv, wp, bq, bk, Wb, bqk, raw);
    gn_stats<<<B_*G_*4, 256, 0, stream>>>(x, raw);
    gn_apply<<<dim3(N_/64, C_/64, B_), 256, 0, stream>>>(x, raw, gnw, gnb, Hn);

    const long long sHn = (long long)N_ * C_;        // bytes (fp8)
    const long long sQK = (long long)N_ * 1024;
    const long long sV  = (long long)C_ * N_;
    const long long sS  = (long long)N_ * N_;

    // QK fused: [4096,1024] = (Hn @ [Wq;Wk]^T)/16 + bqk -> fp8   (512 blocks)
    gemm_nt8<128,1,3,512><<<dim3(8, 32, 2), 256, 0, stream>>>(
        Hn, C_, sHn, Wb, C_, 0, QK8, 1024, sQK, bqk, nullptr, 1.f/16.f);
    // V: [512,4096] = (Wv @ Hn^T)/16 + bv -> fp8   (512 blocks)
    gemm_nt8<64,2,3,512><<<dim3(32, 8, 2), 256, 0, stream>>>(
        Wb + 2*WN, C_, 0, Hn, C_, sHn, V8, N_, sV, bv, nullptr, 1.f/16.f);

    const float scale = 0.044194173824159216f;       // 512^-0.5
    // S = Q @ K^T * scale -> bf16, both batches (2048 blocks)
    gemm_nt8<128,0,0,512><<<dim3(32, 32, 2), 256, 0, stream>>>(
        QK8, 1024, sQK, QK8 + 512, 1024, sQK, Sb, N_, sS, nullptr, nullptr, scale);
    // softmax rows -> fp8 P*256 in place (2048 blocks)
    softmax_rows<<<B_*N_/4, 256, 0, stream>>>(Sb);
    // Ot = (P8 @ V8^T) * 16/256 -> fp8 (x16)   (256 blocks)
    gemm_nt8<128,0,3,4096><<<dim3(4, 32, 2), 256, 0, stream>>>(
        (const uchar*)Sb, 2*N_, 2*sS, V8, N_, sV, Ot8, C_, sHn, nullptr, nullptr, 1.f/16.f);
    // out[b,o,n] = x + (Wp @ Ot^T)/256 + bp   (512 blocks)
    gemm_nt8<64,2,2,512><<<dim3(32, 8, 2), 256, 0, stream>>>(
        Wb + 3*WN, C_, 0, Ot8, C_, sHn, out, N_, (long long)C_*N_, bp, x, 1.f/256.f);
}

// Round 9
// 210.379 us; speedup vs baseline: 2.0866x; 1.0683x over previous
//
#include <hip/hip_runtime.h>
#include <hip/hip_bf16.h>
#include <stdint.h>

typedef short short8 __attribute__((ext_vector_type(8)));
typedef float f32x4  __attribute__((ext_vector_type(4)));
typedef unsigned char uchar;

#define B_ 2
#define C_ 512
#define N_ 4096
#define G_ 32
#define WN (C_ * C_)

static __device__ __forceinline__ short f2bf(float f) {
    return __builtin_bit_cast(short, __float2bfloat16(f));
}
static __device__ __forceinline__ float bf2f(short s) {
    return __builtin_bit_cast(float, ((unsigned)(unsigned short)s) << 16);
}
static __device__ __forceinline__ uchar f2fp8(float f) {
    return (uchar)(__builtin_amdgcn_cvt_pk_fp8_f32(f, f, 0, false) & 0xff);
}

// Barrier that does NOT drain vmcnt (cross-wave comm is LDS-only in the GEMMs).
// imm 0xC07F = vmcnt(63) expcnt(7) lgkmcnt(0).
static __device__ __forceinline__ void wg_barrier_lds() {
    __builtin_amdgcn_s_waitcnt(0xC07F);
    __builtin_amdgcn_s_barrier();
}

// ---- fused prep: fp8-convert 4 weights (x16 prescale), pack bq|bk, zero gn acc ----
__global__ void prep(const float* __restrict__ wq, const float* __restrict__ wk,
                     const float* __restrict__ wv, const float* __restrict__ wp,
                     const float* __restrict__ bq, const float* __restrict__ bk,
                     uchar* __restrict__ Wb, float* __restrict__ bqk,
                     float* __restrict__ raw) {
    int i = blockIdx.x * 256 + threadIdx.x;
    if (i < 4 * WN) {
        const float* src = (i < 2*WN) ? ((i < WN) ? wq : wk) : ((i < 3*WN) ? wv : wp);
        Wb[i] = f2fp8(src[i & (WN - 1)] * 16.f);
    } else if (i < 4*WN + 1024) {
        int j = i - 4*WN;
        bqk[j] = (j < C_) ? bq[j] : bk[j - C_];
    } else if (i < 4*WN + 1024 + 128) {
        raw[i - (4*WN + 1024)] = 0.f;
    }
}

// ---- gn partial stats: 4 blocks per (b,g), atomicAdd raw sums ----
__global__ void gn_stats(const float* __restrict__ x, float* __restrict__ raw) {
    const int bg = blockIdx.x >> 2, qt = blockIdx.x & 3;
    const float4* p = (const float4*)(x + (size_t)bg * 16 * N_ + (size_t)qt * 4 * N_);
    int tid = threadIdx.x;
    float s = 0.f, sq = 0.f;
    #pragma unroll
    for (int rep = 0; rep < 16; rep++) {
        float4 t = p[rep * 256 + tid];
        s  += t.x + t.y + t.z + t.w;
        sq += t.x*t.x + t.y*t.y + t.z*t.z + t.w*t.w;
    }
    __shared__ float rs[256], rq[256];
    rs[tid] = s; rq[tid] = sq;
    __syncthreads();
    for (int h = 128; h > 0; h >>= 1) {
        if (tid < h) { rs[tid] += rs[tid+h]; rq[tid] += rq[tid+h]; }
        __syncthreads();
    }
    if (tid == 0) {
        atomicAdd(&raw[bg*2+0], rs[0]);
        atomicAdd(&raw[bg*2+1], rq[0]);
    }
}

// ---- groupnorm apply + transpose: x[b,c,n] fp32 -> Hn[b,n,c] fp8 ----
__global__ void gn_apply(const float* __restrict__ x, const float* __restrict__ raw,
                         const float* __restrict__ gw, const float* __restrict__ gb,
                         uchar* __restrict__ hn) {
    __shared__ uchar t[64 * 68];
    const int n0 = blockIdx.x * 64, c0 = blockIdx.y * 64, b = blockIdx.z;
    const int lane = threadIdx.x & 63, w = threadIdx.x >> 6;
    const float inv = 1.f / (16.f * N_);
    #pragma unroll
    for (int rep = 0; rep < 16; rep++) {
        int c  = rep * 4 + w;
        int cc = c0 + c;
        int g  = cc >> 4;
        float mean = raw[(b*G_ + g)*2 + 0] * inv;
        float var  = raw[(b*G_ + g)*2 + 1] * inv - mean * mean;
        float rstd = rsqrtf(var + 1e-6f);
        float sc = gw[cc] * rstd;
        float bi = gb[cc] - mean * sc;
        float v = x[((size_t)(b*C_ + cc)) * N_ + n0 + lane];
        t[lane*68 + c] = f2fp8(v * sc + bi);
    }
    __syncthreads();
    #pragma unroll
    for (int rep = 0; rep < 16; rep++) {
        int n = rep * 4 + w;
        hn[((size_t)(b*N_ + n0 + n)) * C_ + c0 + lane] = t[n*68 + lane];
    }
}

// ---- generic fp8 NT GEMM, ring-4 prefetch, lgkm-only barriers ----
// C[m,n] = alpha * sum_k A[m,k]*B[n,k] (+bias) (+residual)
// A,B fp8 e4m3; lda/ldb/sAz/sBz in BYTES; ldc/sCz in elements.
// BK=64 (one 64-byte LDS row per matrix row). 8B-slot XOR swizzle with
// h(row) = (row>>1)&7 (conflict-free: bank = 16*(fm&1) + 2*(q^h) is injective
// over the 16 fm for each q — fixes the fm/fm+8 collision of the e=fm&7 map):
//   slot s of row r holds k-chunk s ^ h(r)
//   writer: 16B chunk c -> pair c ^ ((r>>2)&3), halves swapped iff (r>>1)&1
//   reader: k-group q at byte ((q ^ ((fm>>1)&7)) << 3), q+4 likewise.
// BIAS_MODE: 0 none, 1 per-col, 2 per-row. OUT_MODE: 0 bf16, 2 fp32+res, 3 fp8.
// BM in {64,128}; BN=128; 4 waves (2x2). K multiple of 256.
template<int BM, int BIAS_MODE, int OUT_MODE, int K>
__global__ __launch_bounds__(256, 2)
void gemm_nt8(const uchar* __restrict__ A, int lda, long long sAz,
              const uchar* __restrict__ Bm, int ldb, long long sBz,
              void* __restrict__ Cv, int ldc, long long sCz,
              const float* __restrict__ bias,
              const float* __restrict__ res,
              float alpha) {
    constexpr int MI = BM / 32;
    constexpr int T  = K / 64;
    __shared__ uchar As[2][BM * 64];
    __shared__ uchar Bs[2][128 * 64];
    const int tid  = threadIdx.x;
    const int lane = tid & 63;
    const int wid  = tid >> 6;
    const int wr   = wid >> 1;
    const int wc   = wid & 1;
    const int m0 = blockIdx.y * BM;
    const int n0 = blockIdx.x * 128;
    const int z  = blockIdx.z;

    const int r = tid >> 2;                  // 0..63
    const int c = tid & 3;                   // 16B chunk in 64B row
    const int wofs = r * 64 + ((c ^ ((r >> 2) & 3)) << 4);
    const bool swp = ((r >> 1) & 1) != 0;

    const uchar* Ap  = A  + sAz * z + (size_t)(m0 + r) * lda + c * 16;
    const uchar* Ap1 = Ap + (size_t)64 * lda;
    const uchar* Bp  = Bm + sBz * z + (size_t)(n0 + r) * ldb + c * 16;
    const uchar* Bp1 = Bp + (size_t)64 * ldb;

    f32x4 acc[MI][4];
    #pragma unroll
    for (int i = 0; i < MI; i++)
        #pragma unroll
        for (int j = 0; j < 4; j++)
            acc[i][j] = f32x4{0.f, 0.f, 0.f, 0.f};

    const int fm = lane & 15;
    const int q  = lane >> 4;
    const int h  = (fm >> 1) & 7;
    const int ro0 = ((q ^ h) << 3);
    const int ro1 = (((4 + q) ^ h) << 3);

    short8 ra[4][2], rb[4][2];

    #define ST16(dst, v) do { short8 _w; \
        if (swp) { _w[0]=(v)[4];_w[1]=(v)[5];_w[2]=(v)[6];_w[3]=(v)[7]; \
                   _w[4]=(v)[0];_w[5]=(v)[1];_w[6]=(v)[2];_w[7]=(v)[3]; } \
        else _w = (v); \
        *(short8*)(dst) = _w; } while (0)
    #define LOADG(s, kb) do { ra[s][0] = *(const short8*)(Ap  + (kb)); \
                              if (BM == 128) ra[s][1] = *(const short8*)(Ap1 + (kb)); \
                              rb[s][0] = *(const short8*)(Bp  + (kb)); \
                              rb[s][1] = *(const short8*)(Bp1 + (kb)); } while (0)
    #define STORES(b, s) do { ST16(&As[b][wofs], ra[s][0]); \
                              if (BM == 128) ST16(&As[b][wofs + 64*64], ra[s][1]); \
                              ST16(&Bs[b][wofs], rb[s][0]); ST16(&Bs[b][wofs + 64*64], rb[s][1]); } while (0)
    #define STEP(bt, J, DO_STORE, DO_LOAD) do { \
        long af0[MI], af1[MI], bf0[4], bf1[4]; \
        _Pragma("unroll") \
        for (int i = 0; i < MI; i++) { \
            int ar = (wr*(BM/2) + i*16 + fm) * 64; \
            af0[i] = *(const long*)&As[(J)&1][ar + ro0]; \
            af1[i] = *(const long*)&As[(J)&1][ar + ro1]; \
        } \
        _Pragma("unroll") \
        for (int i = 0; i < 4; i++) { \
            int br = (wc*64 + i*16 + fm) * 64; \
            bf0[i] = *(const long*)&Bs[(J)&1][br + ro0]; \
            bf1[i] = *(const long*)&Bs[(J)&1][br + ro1]; \
        } \
        if (DO_STORE) STORES(((J)+1)&1, ((J)+1)&3); \
        if (DO_LOAD)  LOADG(((J)+3)&3, ((bt)+(J)+3)*64); \
        _Pragma("unroll") \
        for (int mi = 0; mi < MI; mi++) \
            _Pragma("unroll") \
            for (int ni = 0; ni < 4; ni++) \
                acc[mi][ni] = __builtin_amdgcn_mfma_f32_16x16x32_fp8_fp8(af0[mi], bf0[ni], acc[mi][ni], 0, 0, 0); \
        _Pragma("unroll") \
        for (int mi = 0; mi < MI; mi++) \
            _Pragma("unroll") \
            for (int ni = 0; ni < 4; ni++) \
                acc[mi][ni] = __builtin_amdgcn_mfma_f32_16x16x32_fp8_fp8(af1[mi], bf1[ni], acc[mi][ni], 0, 0, 0); \
        wg_barrier_lds(); \
    } while (0)

    LOADG(0, 0);
    LOADG(1, 64);
    LOADG(2, 128);
    STORES(0, 0);
    wg_barrier_lds();

    for (int m = 0; m < T/4 - 1; m++) {
        const int bt = m * 4;
        STEP(bt, 0, true, true);
        STEP(bt, 1, true, true);
        STEP(bt, 2, true, true);
        STEP(bt, 3, true, true);
    }
    {
        const int bt = T - 4;
        STEP(bt, 0, true,  true);
        STEP(bt, 1, true,  false);
        STEP(bt, 2, true,  false);
        STEP(bt, 3, false, false);
    }
    #undef ST16
    #undef LOADG
    #undef STORES
    #undef STEP

    const int colb = n0 + wc*64 + fm;
    const int rowb = m0 + wr*(BM/2) + (q << 2);
    #pragma unroll
    for (int mi = 0; mi < MI; mi++) {
        #pragma unroll
        for (int ni = 0; ni < 4; ni++) {
            int cc = colb + ni*16;
            float cb = (BIAS_MODE == 1) ? bias[cc] : 0.f;
            #pragma unroll
            for (int rr4 = 0; rr4 < 4; rr4++) {
                int rr = rowb + mi*16 + rr4;
                float val = acc[mi][ni][rr4] * alpha + cb;
                if (BIAS_MODE == 2) val += bias[rr];
                long long idx = sCz * z + (long long)rr * ldc + cc;
                if (OUT_MODE == 0)      ((short*)Cv)[idx] = f2bf(val);
                else if (OUT_MODE == 2) ((float*)Cv)[idx] = val + res[idx];
                else                    ((uchar*)Cv)[idx] = f2fp8(val);
            }
        }
    }
}

// ---- softmax: one wave per row; bf16 in, fp8(x256) out in place at row head ----
__global__ void softmax_rows(short* __restrict__ S) {
    const int lane = threadIdx.x & 63;
    const int wave = threadIdx.x >> 6;
    const int row  = blockIdx.x * 4 + wave;          // 0..8191
    short8* rp = (short8*)(S + (size_t)row * N_);
    float f[64];
    float mx = -3.0e38f;
    #pragma unroll
    for (int c = 0; c < 8; c++) {
        short8 d = rp[c * 64 + lane];
        #pragma unroll
        for (int j = 0; j < 8; j++) {
            f[c*8 + j] = bf2f(d[j]);
            mx = fmaxf(mx, f[c*8 + j]);
        }
    }
    #pragma unroll
    for (int off = 32; off > 0; off >>= 1)
        mx = fmaxf(mx, __shfl_xor(mx, off));
    float sum = 0.f;
    #pragma unroll
    for (int j = 0; j < 64; j++) { f[j] = __expf(f[j] - mx); sum += f[j]; }
    #pragma unroll
    for (int off = 32; off > 0; off >>= 1)
        sum += __shfl_xor(sum, off);
    float inv = 256.f / sum;                         // store P*256 in fp8
    uchar* ob = (uchar*)(S + (size_t)row * N_);
    #pragma unroll
    for (int c = 0; c < 8; c++) {
        int lo = 0, hi = 0;
        lo = __builtin_amdgcn_cvt_pk_fp8_f32(f[c*8+0]*inv, f[c*8+1]*inv, lo, false);
        lo = __builtin_amdgcn_cvt_pk_fp8_f32(f[c*8+2]*inv, f[c*8+3]*inv, lo, true);
        hi = __builtin_amdgcn_cvt_pk_fp8_f32(f[c*8+4]*inv, f[c*8+5]*inv, hi, false);
        hi = __builtin_amdgcn_cvt_pk_fp8_f32(f[c*8+6]*inv, f[c*8+7]*inv, hi, true);
        unsigned long long o = ((unsigned long long)(unsigned)hi << 32) | (unsigned)lo;
        *(unsigned long long*)&ob[(size_t)(c * 64 + lane) * 8] = o;
    }
}

extern "C" void kernel_launch(void* const* d_in, const int* in_sizes, int n_in,
                              void* d_out, int out_size, void* d_ws, size_t ws_size,
                              hipStream_t stream) {
    const float* x   = (const float*)d_in[0];
    const float* gnw = (const float*)d_in[1];
    const float* gnb = (const float*)d_in[2];
    const float* wq  = (const float*)d_in[3];
    const float* bq  = (const float*)d_in[4];
    const float* wk  = (const float*)d_in[5];
    const float* bk  = (const float*)d_in[6];
    const float* wv  = (const float*)d_in[7];
    const float* bv  = (const float*)d_in[8];
    const float* wp  = (const float*)d_in[9];
    const float* bp  = (const float*)d_in[10];
    float* out = (float*)d_out;
    char*  ws  = (char*)d_ws;

    // workspace layout (~88 MB)
    float* raw = (float*)(ws + 0);                   // 512 B
    float* bqk = (float*)(ws + 8192);                // 4 KB
    uchar* Wb  = (uchar*)(ws + 65536);               // 1 MB  [4][512][512] fp8 (x16)
    uchar* Hn  = (uchar*)(ws + (2ull  << 20));       // 4 MB  [2][4096][512] fp8
    uchar* QK8 = (uchar*)(ws + (8ull  << 20));       // 8 MB  [2][4096][1024] fp8 (Q|K)
    uchar* V8  = (uchar*)(ws + (16ull << 20));       // 4 MB  [2][512][4096] fp8
    uchar* Ot8 = (uchar*)(ws + (20ull << 20));       // 4 MB  [2][4096][512] fp8 (x16)
    short* Sb  = (short*)(ws + (24ull << 20));       // 64 MB [2][4096][4096] bf16 (P fp8 in place)

    prep<<<(4*WN + 1024 + 128 + 255)/256, 256, 0, stream>>>(wq, wk, wv, wp, bq, bk, Wb, bqk, raw);
    gn_stats<<<B_*G_*4, 256, 0, stream>>>(x, raw);
    gn_apply<<<dim3(N_/64, C_/64, B_), 256, 0, stream>>>(x, raw, gnw, gnb, Hn);

    const long long sHn = (long long)N_ * C_;        // bytes (fp8)
    const long long sQK = (long long)N_ * 1024;
    const long long sV  = (long long)C_ * N_;
    const long long sS  = (long long)N_ * N_;

    // QK fused: [4096,1024] = (Hn @ [Wq;Wk]^T)/16 + bqk -> fp8   (512 blocks)
    gemm_nt8<128,1,3,512><<<dim3(8, 32, 2), 256, 0, stream>>>(
        Hn, C_, sHn, Wb, C_, 0, QK8, 1024, sQK, bqk, nullptr, 1.f/16.f);
    // V: [512,4096] = (Wv @ Hn^T)/16 + bv -> fp8   (512 blocks)
    gemm_nt8<64,2,3,512><<<dim3(32, 8, 2), 256, 0, stream>>>(
        Wb + 2*WN, C_, 0, Hn, C_, sHn, V8, N_, sV, bv, nullptr, 1.f/16.f);

    const float scale = 0.044194173824159216f;       // 512^-0.5
    // S = Q @ K^T * scale -> bf16, both batches (2048 blocks)
    gemm_nt8<128,0,0,512><<<dim3(32, 32, 2), 256, 0, stream>>>(
        QK8, 1024, sQK, QK8 + 512, 1024, sQK, Sb, N_, sS, nullptr, nullptr, scale);
    // softmax rows -> fp8 P*256 in place (2048 blocks)
    softmax_rows<<<B_*N_/4, 256, 0, stream>>>(Sb);
    // Ot = (P8 @ V8^T) * 16/256 -> fp8 (x16)   (512 blocks, BM=64 -> 2/CU)
    gemm_nt8<64,0,3,4096><<<dim3(4, 64, 2), 256, 0, stream>>>(
        (const uchar*)Sb, 2*N_, 2*sS, V8, N_, sV, Ot8, C_, sHn, nullptr, nullptr, 1.f/16.f);
    // out[b,o,n] = x + (Wp @ Ot^T)/256 + bp   (512 blocks)
    gemm_nt8<64,2,2,512><<<dim3(32, 8, 2), 256, 0, stream>>>(
        Wb + 3*WN, C_, 0, Ot8, C_, sHn, out, N_, (long long)C_*N_, bp, x, 1.f/256.f);
}

// Round 10
// 208.011 us; speedup vs baseline: 2.1103x; 1.0114x over previous
//
#include <hip/hip_runtime.h>
#include <hip/hip_bf16.h>
#include <stdint.h>

typedef short short8 __attribute__((ext_vector_type(8)));
typedef float f32x4  __attribute__((ext_vector_type(4)));
typedef float f32x2  __attribute__((ext_vector_type(2)));
typedef unsigned char uchar;

#define B_ 2
#define C_ 512
#define N_ 4096
#define G_ 32
#define WN (C_ * C_)
#define PREP_BLOCKS 4101   // ceil((4*WN + 1024)/256)

static __device__ __forceinline__ short f2bf(float f) {
    return __builtin_bit_cast(short, __float2bfloat16(f));
}
static __device__ __forceinline__ uchar f2fp8(float f) {
    return (uchar)(__builtin_amdgcn_cvt_pk_fp8_f32(f, f, 0, false) & 0xff);
}

// Barrier that does NOT drain vmcnt (cross-wave comm is LDS-only in the GEMMs).
// imm 0xC07F = vmcnt(63) expcnt(7) lgkmcnt(0).
static __device__ __forceinline__ void wg_barrier_lds() {
    __builtin_amdgcn_s_waitcnt(0xC07F);
    __builtin_amdgcn_s_barrier();
}

// ---- merged prep + gn partial stats (no atomics: each stats block owns a slot) ----
__global__ void prep_stats(const float* __restrict__ wq, const float* __restrict__ wk,
                           const float* __restrict__ wv, const float* __restrict__ wp,
                           const float* __restrict__ bq, const float* __restrict__ bk,
                           const float* __restrict__ x,
                           uchar* __restrict__ Wb, float* __restrict__ bqk,
                           float* __restrict__ raw) {
    if (blockIdx.x < PREP_BLOCKS) {
        int i = blockIdx.x * 256 + threadIdx.x;
        if (i < 4 * WN) {
            const float* src = (i < 2*WN) ? ((i < WN) ? wq : wk) : ((i < 3*WN) ? wv : wp);
            Wb[i] = f2fp8(src[i & (WN - 1)] * 16.f);
        } else if (i < 4*WN + 1024) {
            int j = i - 4*WN;
            bqk[j] = (j < C_) ? bq[j] : bk[j - C_];
        }
        return;
    }
    // stats part: 256 blocks, 4 per (b,g); partials raw[(bg*4+qt)*2 + {0,1}]
    const int idx = blockIdx.x - PREP_BLOCKS;        // 0..255
    const int bg = idx >> 2, qt = idx & 3;
    const float4* p = (const float4*)(x + (size_t)bg * 16 * N_ + (size_t)qt * 4 * N_);
    int tid = threadIdx.x;
    float s = 0.f, sq = 0.f;
    #pragma unroll
    for (int rep = 0; rep < 16; rep++) {
        float4 t = p[rep * 256 + tid];
        s  += t.x + t.y + t.z + t.w;
        sq += t.x*t.x + t.y*t.y + t.z*t.z + t.w*t.w;
    }
    __shared__ float rs[256], rq[256];
    rs[tid] = s; rq[tid] = sq;
    __syncthreads();
    for (int h = 128; h > 0; h >>= 1) {
        if (tid < h) { rs[tid] += rs[tid+h]; rq[tid] += rq[tid+h]; }
        __syncthreads();
    }
    if (tid == 0) {
        raw[idx*2+0] = rs[0];
        raw[idx*2+1] = rq[0];
    }
}

// ---- groupnorm apply + transpose: x[b,c,n] fp32 -> Hn[b,n,c] fp8 ----
__global__ void gn_apply(const float* __restrict__ x, const float* __restrict__ raw,
                         const float* __restrict__ gw, const float* __restrict__ gb,
                         uchar* __restrict__ hn) {
    __shared__ uchar t[64 * 68];
    const int n0 = blockIdx.x * 64, c0 = blockIdx.y * 64, b = blockIdx.z;
    const int lane = threadIdx.x & 63, w = threadIdx.x >> 6;
    const float inv = 1.f / (16.f * N_);
    #pragma unroll
    for (int rep = 0; rep < 16; rep++) {
        int c  = rep * 4 + w;
        int cc = c0 + c;
        int g  = cc >> 4;
        int base = (b*G_ + g) * 8;
        float mean = (raw[base] + raw[base+2] + raw[base+4] + raw[base+6]) * inv;
        float var  = (raw[base+1] + raw[base+3] + raw[base+5] + raw[base+7]) * inv - mean * mean;
        float rstd = rsqrtf(var + 1e-6f);
        float sc = gw[cc] * rstd;
        float bi = gb[cc] - mean * sc;
        float v = x[((size_t)(b*C_ + cc)) * N_ + n0 + lane];
        t[lane*68 + c] = f2fp8(v * sc + bi);
    }
    __syncthreads();
    #pragma unroll
    for (int rep = 0; rep < 16; rep++) {
        int n = rep * 4 + w;
        hn[((size_t)(b*N_ + n0 + n)) * C_ + c0 + lane] = t[n*68 + lane];
    }
}

// ---- generic fp8 NT GEMM, ring-4 prefetch, lgkm-only barriers ----
// C[m,n] = alpha * sum_k A[m,k]*B[n,k] (+bias) (+residual)
// A,B fp8 e4m3; lda/ldb/sAz/sBz in BYTES; ldc/sCz in elements.
// BK=64 (one 64-byte LDS row per matrix row). Conflict-free 8B-slot XOR swizzle
// with h(row)=(row>>1)&7 (verified round 9: SQ_LDS_BANK_CONFLICT=0):
//   writer: 16B chunk c -> pair c ^ ((r>>2)&3), halves swapped iff (r>>1)&1
//   reader: k-group q at byte ((q ^ ((fm>>1)&7)) << 3), q+4 likewise.
// BIAS_MODE: 0 none, 1 per-col, 2 per-row. OUT_MODE: 0 bf16, 2 fp32+res, 3 fp8.
// BM in {64,128}; BN=128; 4 waves (2x2). K multiple of 256.
template<int BM, int BIAS_MODE, int OUT_MODE, int K>
__global__ __launch_bounds__(256, 2)
void gemm_nt8(const uchar* __restrict__ A, int lda, long long sAz,
              const uchar* __restrict__ Bm, int ldb, long long sBz,
              void* __restrict__ Cv, int ldc, long long sCz,
              const float* __restrict__ bias,
              const float* __restrict__ res,
              float alpha) {
    constexpr int MI = BM / 32;
    constexpr int T  = K / 64;
    __shared__ uchar As[2][BM * 64];
    __shared__ uchar Bs[2][128 * 64];
    const int tid  = threadIdx.x;
    const int lane = tid & 63;
    const int wid  = tid >> 6;
    const int wr   = wid >> 1;
    const int wc   = wid & 1;
    const int m0 = blockIdx.y * BM;
    const int n0 = blockIdx.x * 128;
    const int z  = blockIdx.z;

    const int r = tid >> 2;                  // 0..63
    const int c = tid & 3;                   // 16B chunk in 64B row
    const int wofs = r * 64 + ((c ^ ((r >> 2) & 3)) << 4);
    const bool swp = ((r >> 1) & 1) != 0;

    const uchar* Ap  = A  + sAz * z + (size_t)(m0 + r) * lda + c * 16;
    const uchar* Ap1 = Ap + (size_t)64 * lda;
    const uchar* Bp  = Bm + sBz * z + (size_t)(n0 + r) * ldb + c * 16;
    const uchar* Bp1 = Bp + (size_t)64 * ldb;

    f32x4 acc[MI][4];
    #pragma unroll
    for (int i = 0; i < MI; i++)
        #pragma unroll
        for (int j = 0; j < 4; j++)
            acc[i][j] = f32x4{0.f, 0.f, 0.f, 0.f};

    const int fm = lane & 15;
    const int q  = lane >> 4;
    const int h  = (fm >> 1) & 7;
    const int ro0 = ((q ^ h) << 3);
    const int ro1 = (((4 + q) ^ h) << 3);

    short8 ra[4][2], rb[4][2];

    #define ST16(dst, v) do { short8 _w; \
        if (swp) { _w[0]=(v)[4];_w[1]=(v)[5];_w[2]=(v)[6];_w[3]=(v)[7]; \
                   _w[4]=(v)[0];_w[5]=(v)[1];_w[6]=(v)[2];_w[7]=(v)[3]; } \
        else _w = (v); \
        *(short8*)(dst) = _w; } while (0)
    #define LOADG(s, kb) do { ra[s][0] = *(const short8*)(Ap  + (kb)); \
                              if (BM == 128) ra[s][1] = *(const short8*)(Ap1 + (kb)); \
                              rb[s][0] = *(const short8*)(Bp  + (kb)); \
                              rb[s][1] = *(const short8*)(Bp1 + (kb)); } while (0)
    #define STORES(b, s) do { ST16(&As[b][wofs], ra[s][0]); \
                              if (BM == 128) ST16(&As[b][wofs + 64*64], ra[s][1]); \
                              ST16(&Bs[b][wofs], rb[s][0]); ST16(&Bs[b][wofs + 64*64], rb[s][1]); } while (0)
    #define STEP(bt, J, DO_STORE, DO_LOAD) do { \
        long af0[MI], af1[MI], bf0[4], bf1[4]; \
        _Pragma("unroll") \
        for (int i = 0; i < MI; i++) { \
            int ar = (wr*(BM/2) + i*16 + fm) * 64; \
            af0[i] = *(const long*)&As[(J)&1][ar + ro0]; \
            af1[i] = *(const long*)&As[(J)&1][ar + ro1]; \
        } \
        _Pragma("unroll") \
        for (int i = 0; i < 4; i++) { \
            int br = (wc*64 + i*16 + fm) * 64; \
            bf0[i] = *(const long*)&Bs[(J)&1][br + ro0]; \
            bf1[i] = *(const long*)&Bs[(J)&1][br + ro1]; \
        } \
        if (DO_STORE) STORES(((J)+1)&1, ((J)+1)&3); \
        if (DO_LOAD)  LOADG(((J)+3)&3, ((bt)+(J)+3)*64); \
        _Pragma("unroll") \
        for (int mi = 0; mi < MI; mi++) \
            _Pragma("unroll") \
            for (int ni = 0; ni < 4; ni++) \
                acc[mi][ni] = __builtin_amdgcn_mfma_f32_16x16x32_fp8_fp8(af0[mi], bf0[ni], acc[mi][ni], 0, 0, 0); \
        _Pragma("unroll") \
        for (int mi = 0; mi < MI; mi++) \
            _Pragma("unroll") \
            for (int ni = 0; ni < 4; ni++) \
                acc[mi][ni] = __builtin_amdgcn_mfma_f32_16x16x32_fp8_fp8(af1[mi], bf1[ni], acc[mi][ni], 0, 0, 0); \
        wg_barrier_lds(); \
    } while (0)

    LOADG(0, 0);
    LOADG(1, 64);
    LOADG(2, 128);
    STORES(0, 0);
    wg_barrier_lds();

    for (int m = 0; m < T/4 - 1; m++) {
        const int bt = m * 4;
        STEP(bt, 0, true, true);
        STEP(bt, 1, true, true);
        STEP(bt, 2, true, true);
        STEP(bt, 3, true, true);
    }
    {
        const int bt = T - 4;
        STEP(bt, 0, true,  true);
        STEP(bt, 1, true,  false);
        STEP(bt, 2, true,  false);
        STEP(bt, 3, false, false);
    }
    #undef ST16
    #undef LOADG
    #undef STORES
    #undef STEP

    const int colb = n0 + wc*64 + fm;
    const int rowb = m0 + wr*(BM/2) + (q << 2);
    #pragma unroll
    for (int mi = 0; mi < MI; mi++) {
        #pragma unroll
        for (int ni = 0; ni < 4; ni++) {
            int cc = colb + ni*16;
            float cb = (BIAS_MODE == 1) ? bias[cc] : 0.f;
            #pragma unroll
            for (int rr4 = 0; rr4 < 4; rr4++) {
                int rr = rowb + mi*16 + rr4;
                float val = acc[mi][ni][rr4] * alpha + cb;
                if (BIAS_MODE == 2) val += bias[rr];
                long long idx = sCz * z + (long long)rr * ldc + cc;
                if (OUT_MODE == 0)      ((short*)Cv)[idx] = f2bf(val);
                else if (OUT_MODE == 2) ((float*)Cv)[idx] = val + res[idx];
                else                    ((uchar*)Cv)[idx] = f2fp8(val);
            }
        }
    }
}

// ---- softmax: one wave per row; fp8(S*16) in, fp8(P*256) out, in place ----
__global__ void softmax_rows8(uchar* __restrict__ S) {
    const int lane = threadIdx.x & 63;
    const int wave = threadIdx.x >> 6;
    const size_t row = (size_t)blockIdx.x * 4 + wave;   // 0..8191
    uint4* rp = (uint4*)(S + row * N_);                 // 256 uint4 per row
    uint4 d[4];
    float f[64];
    float mx = -3.0e38f;
    #pragma unroll
    for (int c = 0; c < 4; c++) {
        d[c] = rp[c * 64 + lane];
        unsigned wv[4] = {d[c].x, d[c].y, d[c].z, d[c].w};
        #pragma unroll
        for (int u = 0; u < 4; u++) {
            f32x2 lo = __builtin_amdgcn_cvt_pk_f32_fp8(wv[u], false);
            f32x2 hi = __builtin_amdgcn_cvt_pk_f32_fp8(wv[u], true);
            int b = c*16 + u*4;
            f[b+0] = lo[0]; f[b+1] = lo[1]; f[b+2] = hi[0]; f[b+3] = hi[1];
            mx = fmaxf(mx, fmaxf(fmaxf(lo[0], lo[1]), fmaxf(hi[0], hi[1])));
        }
    }
    #pragma unroll
    for (int off = 32; off > 0; off >>= 1)
        mx = fmaxf(mx, __shfl_xor(mx, off));
    float sum = 0.f;
    const float k = 0.0625f;                            // decoded = S*16
    #pragma unroll
    for (int j = 0; j < 64; j++) { f[j] = __expf((f[j] - mx) * k); sum += f[j]; }
    #pragma unroll
    for (int off = 32; off > 0; off >>= 1)
        sum += __shfl_xor(sum, off);
    float inv = 256.f / sum;                            // store P*256 fp8
    #pragma unroll
    for (int c = 0; c < 4; c++) {
        unsigned wv[4];
        #pragma unroll
        for (int u = 0; u < 4; u++) {
            int b = c*16 + u*4;
            int o = 0;
            o = __builtin_amdgcn_cvt_pk_fp8_f32(f[b+0]*inv, f[b+1]*inv, o, false);
            o = __builtin_amdgcn_cvt_pk_fp8_f32(f[b+2]*inv, f[b+3]*inv, o, true);
            wv[u] = (unsigned)o;
        }
        uint4 ov; ov.x = wv[0]; ov.y = wv[1]; ov.z = wv[2]; ov.w = wv[3];
        rp[c * 64 + lane] = ov;
    }
}

extern "C" void kernel_launch(void* const* d_in, const int* in_sizes, int n_in,
                              void* d_out, int out_size, void* d_ws, size_t ws_size,
                              hipStream_t stream) {
    const float* x   = (const float*)d_in[0];
    const float* gnw = (const float*)d_in[1];
    const float* gnb = (const float*)d_in[2];
    const float* wq  = (const float*)d_in[3];
    const float* bq  = (const float*)d_in[4];
    const float* wk  = (const float*)d_in[5];
    const float* bk  = (const float*)d_in[6];
    const float* wv  = (const float*)d_in[7];
    const float* bv  = (const float*)d_in[8];
    const float* wp  = (const float*)d_in[9];
    const float* bp  = (const float*)d_in[10];
    float* out = (float*)d_out;
    char*  ws  = (char*)d_ws;

    // workspace layout (~56 MB)
    float* raw = (float*)(ws + 0);                   // 2 KB  gn stat partials [64][4][2]
    float* bqk = (float*)(ws + 8192);                // 4 KB
    uchar* Wb  = (uchar*)(ws + 65536);               // 1 MB  [4][512][512] fp8 (x16)
    uchar* Hn  = (uchar*)(ws + (2ull  << 20));       // 4 MB  [2][4096][512] fp8
    uchar* QK8 = (uchar*)(ws + (8ull  << 20));       // 8 MB  [2][4096][1024] fp8 (Q|K)
    uchar* V8  = (uchar*)(ws + (16ull << 20));       // 4 MB  [2][512][4096] fp8
    uchar* Ot8 = (uchar*)(ws + (20ull << 20));       // 4 MB  [2][4096][512] fp8 (x16)
    uchar* Sb  = (uchar*)(ws + (24ull << 20));       // 32 MB [2][4096][4096] fp8 (S*16, then P*256)

    prep_stats<<<PREP_BLOCKS + 256, 256, 0, stream>>>(wq, wk, wv, wp, bq, bk, x, Wb, bqk, raw);
    gn_apply<<<dim3(N_/64, C_/64, B_), 256, 0, stream>>>(x, raw, gnw, gnb, Hn);

    const long long sHn = (long long)N_ * C_;        // bytes (fp8)
    const long long sQK = (long long)N_ * 1024;
    const long long sV  = (long long)C_ * N_;
    const long long sS  = (long long)N_ * N_;

    // QK fused: [4096,1024] = (Hn @ [Wq;Wk]^T)/16 + bqk -> fp8   (512 blocks)
    gemm_nt8<128,1,3,512><<<dim3(8, 32, 2), 256, 0, stream>>>(
        Hn, C_, sHn, Wb, C_, 0, QK8, 1024, sQK, bqk, nullptr, 1.f/16.f);
    // V: [512,4096] = (Wv @ Hn^T)/16 + bv -> fp8   (512 blocks)
    gemm_nt8<64,2,3,512><<<dim3(32, 8, 2), 256, 0, stream>>>(
        Wb + 2*WN, C_, 0, Hn, C_, sHn, V8, N_, sV, bv, nullptr, 1.f/16.f);

    // S*16 = Q @ K^T * (scale*16) -> fp8, both batches (2048 blocks)
    const float alphaS = 0.044194173824159216f * 16.f;   // 512^-0.5 * 16
    gemm_nt8<128,0,3,512><<<dim3(32, 32, 2), 256, 0, stream>>>(
        QK8, 1024, sQK, QK8 + 512, 1024, sQK, Sb, N_, sS, nullptr, nullptr, alphaS);
    // softmax rows: fp8 in/out in place (2048 blocks)
    softmax_rows8<<<B_*N_/4, 256, 0, stream>>>(Sb);
    // Ot = (P8 @ V8^T) * 16/256 -> fp8 (x16)   (512 blocks, BM=64)
    gemm_nt8<64,0,3,4096><<<dim3(4, 64, 2), 256, 0, stream>>>(
        Sb, N_, sS, V8, N_, sV, Ot8, C_, sHn, nullptr, nullptr, 1.f/16.f);
    // out[b,o,n] = x + (Wp @ Ot^T)/256 + bp   (512 blocks)
    gemm_nt8<64,2,2,512><<<dim3(32, 8, 2), 256, 0, stream>>>(
        Wb + 3*WN, C_, 0, Ot8, C_, sHn, out, N_, (long long)C_*N_, bp, x, 1.f/256.f);
}

// Round 11
// 196.673 us; speedup vs baseline: 2.2320x; 1.0577x over previous
//
#include <hip/hip_runtime.h>
#include <hip/hip_bf16.h>
#include <stdint.h>

typedef short short8 __attribute__((ext_vector_type(8)));
typedef float f32x4  __attribute__((ext_vector_type(4)));
typedef float f32x2  __attribute__((ext_vector_type(2)));
typedef unsigned char uchar;

#define B_ 2
#define C_ 512
#define N_ 4096
#define G_ 32
#define WN (C_ * C_)
#define PREP_BLOCKS 4101   // ceil((4*WN + 1024)/256)

static __device__ __forceinline__ short f2bf(float f) {
    return __builtin_bit_cast(short, __float2bfloat16(f));
}
static __device__ __forceinline__ uchar f2fp8(float f) {
    return (uchar)(__builtin_amdgcn_cvt_pk_fp8_f32(f, f, 0, false) & 0xff);
}

// async global->LDS DMA, 16 B/lane. LDS dest = wave-uniform base + lane*16.
static __device__ __forceinline__ void async16(uchar* lds_wave_base, const uchar* g) {
    auto l  = (__attribute__((address_space(3))) unsigned int*)(uintptr_t)(lds_wave_base);
    auto gg = (const __attribute__((address_space(1))) unsigned int*)(g);
    __builtin_amdgcn_global_load_lds(gg, l, 16, 0, 0);
}

// ---- merged prep + gn partial stats (no atomics: each stats block owns a slot) ----
__global__ void prep_stats(const float* __restrict__ wq, const float* __restrict__ wk,
                           const float* __restrict__ wv, const float* __restrict__ wp,
                           const float* __restrict__ bq, const float* __restrict__ bk,
                           const float* __restrict__ x,
                           uchar* __restrict__ Wb, float* __restrict__ bqk,
                           float* __restrict__ raw) {
    if (blockIdx.x < PREP_BLOCKS) {
        int i = blockIdx.x * 256 + threadIdx.x;
        if (i < 4 * WN) {
            const float* src = (i < 2*WN) ? ((i < WN) ? wq : wk) : ((i < 3*WN) ? wv : wp);
            Wb[i] = f2fp8(src[i & (WN - 1)] * 16.f);
        } else if (i < 4*WN + 1024) {
            int j = i - 4*WN;
            bqk[j] = (j < C_) ? bq[j] : bk[j - C_];
        }
        return;
    }
    const int idx = blockIdx.x - PREP_BLOCKS;        // 0..255
    const int bg = idx >> 2, qt = idx & 3;
    const float4* p = (const float4*)(x + (size_t)bg * 16 * N_ + (size_t)qt * 4 * N_);
    int tid = threadIdx.x;
    float s = 0.f, sq = 0.f;
    #pragma unroll
    for (int rep = 0; rep < 16; rep++) {
        float4 t = p[rep * 256 + tid];
        s  += t.x + t.y + t.z + t.w;
        sq += t.x*t.x + t.y*t.y + t.z*t.z + t.w*t.w;
    }
    __shared__ float rs[256], rq[256];
    rs[tid] = s; rq[tid] = sq;
    __syncthreads();
    for (int h = 128; h > 0; h >>= 1) {
        if (tid < h) { rs[tid] += rs[tid+h]; rq[tid] += rq[tid+h]; }
        __syncthreads();
    }
    if (tid == 0) {
        raw[idx*2+0] = rs[0];
        raw[idx*2+1] = rq[0];
    }
}

// ---- groupnorm apply + transpose: x[b,c,n] fp32 -> Hn[b,n,c] fp8 ----
__global__ void gn_apply(const float* __restrict__ x, const float* __restrict__ raw,
                         const float* __restrict__ gw, const float* __restrict__ gb,
                         uchar* __restrict__ hn) {
    __shared__ uchar t[64 * 68];
    const int n0 = blockIdx.x * 64, c0 = blockIdx.y * 64, b = blockIdx.z;
    const int lane = threadIdx.x & 63, w = threadIdx.x >> 6;
    const float inv = 1.f / (16.f * N_);
    #pragma unroll
    for (int rep = 0; rep < 16; rep++) {
        int c  = rep * 4 + w;
        int cc = c0 + c;
        int g  = cc >> 4;
        int base = (b*G_ + g) * 8;
        float mean = (raw[base] + raw[base+2] + raw[base+4] + raw[base+6]) * inv;
        float var  = (raw[base+1] + raw[base+3] + raw[base+5] + raw[base+7]) * inv - mean * mean;
        float rstd = rsqrtf(var + 1e-6f);
        float sc = gw[cc] * rstd;
        float bi = gb[cc] - mean * sc;
        float v = x[((size_t)(b*C_ + cc)) * N_ + n0 + lane];
        t[lane*68 + c] = f2fp8(v * sc + bi);
    }
    __syncthreads();
    #pragma unroll
    for (int rep = 0; rep < 16; rep++) {
        int n = rep * 4 + w;
        hn[((size_t)(b*N_ + n0 + n)) * C_ + c0 + lane] = t[n*68 + lane];
    }
}

// ---- fp8 NT GEMM with global_load_lds DMA staging + fine-grained vmcnt ----
// C[m,n] = alpha * sum_k A[m,k]*B[n,k] (+bias) (+residual)
// A,B fp8 e4m3; lda/ldb/sAz/sBz in BYTES; ldc/sCz in elements. BK=64.
// Staging: 3-buffer LDS ring, tile t+2 DMA'd at start of step t (prefetch ~2
// steps in flight). Barrier waits only s_waitcnt vmcnt(D) (own share of the
// oldest prefetched tile) — deeper prefetch never drained (AITER pattern).
// LDS layout: 16B-slot s of row r holds global chunk s ^ ((r>>1)&3) (swizzle
// applied on DMA SOURCE address; DMA dest is linear lane*16 — R2-verified).
// Reader: 8B k-chunk q at ro0 = ((q>>1)^((fm>>1)&3))<<4 | (q&1)<<3; q+4 at
// ro0^32. 2-way banked max (free).
// BIAS_MODE: 0 none, 1 per-col, 2 per-row. OUT_MODE: 0 bf16, 2 fp32+res, 3 fp8.
// SWZ: XCD-aware flat-grid decode (grid.x = 4*64*2, siblings-on-one-XCD).
template<int BM, int BIAS_MODE, int OUT_MODE, int K, int SWZ>
__global__ __launch_bounds__(256, 2)
void gemm_nt8(const uchar* __restrict__ A, int lda, long long sAz,
              const uchar* __restrict__ Bm, int ldb, long long sBz,
              void* __restrict__ Cv, int ldc, long long sCz,
              const float* __restrict__ bias,
              const float* __restrict__ res,
              float alpha) {
    constexpr int MI = BM / 32;
    constexpr int T  = K / 64;
    constexpr int D  = (BM == 128) ? 4 : 3;          // DMAs per wave per tile
    constexpr unsigned WAITD = 0xF70u | D;           // vmcnt(D) expcnt(7) lgkm(15)
    constexpr unsigned WAIT0 = 0xF70u;               // vmcnt(0)
    __shared__ uchar As[3][BM * 64];
    __shared__ uchar Bs[3][128 * 64];

    int bx, by, bz;
    if (SWZ) {
        int fid = blockIdx.x;
        int xcd = fid & 7, j = fid >> 3;
        int gg = (j >> 2) * 8 + xcd;                 // sibling group
        bx = j & 3; by = gg & 63; bz = gg >> 6;
    } else { bx = blockIdx.x; by = blockIdx.y; bz = blockIdx.z; }

    const int tid  = threadIdx.x;
    const int lane = tid & 63;
    const int wid  = tid >> 6;
    const int wr   = wid >> 1;
    const int wc   = wid & 1;
    const int m0 = by * BM;
    const int n0 = bx * 128;

    // DMA source: thread (r=tid>>2, c=tid&3) fetches global 16B chunk c^((r>>1)&3)
    const int r  = tid >> 2;
    const int gc = (tid & 3) ^ ((r >> 1) & 3);
    const uchar* Ap  = A  + sAz * bz + (size_t)(m0 + r) * lda + gc * 16;
    const uchar* Ap1 = Ap + (size_t)64 * lda;
    const uchar* Bp  = Bm + sBz * bz + (size_t)(n0 + r) * ldb + gc * 16;
    const uchar* Bp1 = Bp + (size_t)64 * ldb;

    f32x4 acc[MI][4];
    #pragma unroll
    for (int i = 0; i < MI; i++)
        #pragma unroll
        for (int j = 0; j < 4; j++)
            acc[i][j] = f32x4{0.f, 0.f, 0.f, 0.f};

    const int fm  = lane & 15;
    const int q   = lane >> 4;
    const int ro0 = (((q >> 1) ^ ((fm >> 1) & 3)) << 4) | ((q & 1) << 3);
    const int ro1 = ro0 ^ 32;

    #define ISSUE(IB, u) do { size_t _kb = (size_t)(u) * 64; \
        async16(&As[IB][wid * 1024], Ap + _kb); \
        if (BM == 128) async16(&As[IB][4096 + wid * 1024], Ap1 + _kb); \
        async16(&Bs[IB][wid * 1024], Bp + _kb); \
        async16(&Bs[IB][4096 + wid * 1024], Bp1 + _kb); } while (0)

    #define STEP(B, DO_ISSUE, IB, u, DO_BAR, WIMM) do { \
        long af0[MI], af1[MI], bf0[4], bf1[4]; \
        _Pragma("unroll") \
        for (int i = 0; i < MI; i++) { \
            int ar = (wr*(BM/2) + i*16 + fm) * 64; \
            af0[i] = *(const long*)&As[B][ar + ro0]; \
            af1[i] = *(const long*)&As[B][ar + ro1]; \
        } \
        _Pragma("unroll") \
        for (int i = 0; i < 4; i++) { \
            int br = (wc*64 + i*16 + fm) * 64; \
            bf0[i] = *(const long*)&Bs[B][br + ro0]; \
            bf1[i] = *(const long*)&Bs[B][br + ro1]; \
        } \
        if (DO_ISSUE) ISSUE(IB, u); \
        _Pragma("unroll") \
        for (int mi = 0; mi < MI; mi++) \
            _Pragma("unroll") \
            for (int ni = 0; ni < 4; ni++) \
                acc[mi][ni] = __builtin_amdgcn_mfma_f32_16x16x32_fp8_fp8(af0[mi], bf0[ni], acc[mi][ni], 0, 0, 0); \
        _Pragma("unroll") \
        for (int mi = 0; mi < MI; mi++) \
            _Pragma("unroll") \
            for (int ni = 0; ni < 4; ni++) \
                acc[mi][ni] = __builtin_amdgcn_mfma_f32_16x16x32_fp8_fp8(af1[mi], bf1[ni], acc[mi][ni], 0, 0, 0); \
        if (DO_BAR) { __builtin_amdgcn_s_waitcnt(WIMM); __builtin_amdgcn_s_barrier(); } \
    } while (0)

    // prologue: tiles 0,1 in flight; wait own share of tile 0, barrier
    ISSUE(0, 0);
    ISSUE(1, 1);
    __builtin_amdgcn_s_waitcnt(WAITD);
    __builtin_amdgcn_s_barrier();

    constexpr int Gm = (T - 2) / 3;                  // T=8 -> 2, T=64 -> 20
    for (int m = 0; m < Gm; m++) {
        STEP(0, 1, 2, m*3 + 2, 1, WAITD);
        STEP(1, 1, 0, m*3 + 3, 1, WAITD);
        STEP(2, 1, 1, m*3 + 4, 1, WAITD);
    }
    if (T - 3*Gm == 2) {                             // T=8: steps 6,7
        STEP(0, 0, 0, 0, 1, WAIT0);
        STEP(1, 0, 0, 0, 0, 0);
    } else {                                         // T=64: steps 60..63
        STEP(0, 1, 2, T-2, 1, WAITD);
        STEP(1, 1, 0, T-1, 1, WAITD);
        STEP(2, 0, 0, 0, 1, WAIT0);
        STEP(0, 0, 0, 0, 0, 0);
    }
    #undef ISSUE
    #undef STEP

    const int colb = n0 + wc*64 + fm;
    const int rowb = m0 + wr*(BM/2) + (q << 2);
    #pragma unroll
    for (int mi = 0; mi < MI; mi++) {
        #pragma unroll
        for (int ni = 0; ni < 4; ni++) {
            int cc = colb + ni*16;
            float cb = (BIAS_MODE == 1) ? bias[cc] : 0.f;
            #pragma unroll
            for (int rr4 = 0; rr4 < 4; rr4++) {
                int rr = rowb + mi*16 + rr4;
                float val = acc[mi][ni][rr4] * alpha + cb;
                if (BIAS_MODE == 2) val += bias[rr];
                long long idx = sCz * bz + (long long)rr * ldc + cc;
                if (OUT_MODE == 0)      ((short*)Cv)[idx] = f2bf(val);
                else if (OUT_MODE == 2) ((float*)Cv)[idx] = val + res[idx];
                else                    ((uchar*)Cv)[idx] = f2fp8(val);
            }
        }
    }
}

// ---- softmax: one wave per row; fp8(S*16) in, fp8(P*256) out, in place ----
__global__ void softmax_rows8(uchar* __restrict__ S) {
    const int lane = threadIdx.x & 63;
    const int wave = threadIdx.x >> 6;
    const size_t row = (size_t)blockIdx.x * 4 + wave;   // 0..8191
    uint4* rp = (uint4*)(S + row * N_);                 // 256 uint4 per row
    uint4 d[4];
    float f[64];
    float mx = -3.0e38f;
    #pragma unroll
    for (int c = 0; c < 4; c++) {
        d[c] = rp[c * 64 + lane];
        unsigned wv[4] = {d[c].x, d[c].y, d[c].z, d[c].w};
        #pragma unroll
        for (int u = 0; u < 4; u++) {
            f32x2 lo = __builtin_amdgcn_cvt_pk_f32_fp8(wv[u], false);
            f32x2 hi = __builtin_amdgcn_cvt_pk_f32_fp8(wv[u], true);
            int b = c*16 + u*4;
            f[b+0] = lo[0]; f[b+1] = lo[1]; f[b+2] = hi[0]; f[b+3] = hi[1];
            mx = fmaxf(mx, fmaxf(fmaxf(lo[0], lo[1]), fmaxf(hi[0], hi[1])));
        }
    }
    #pragma unroll
    for (int off = 32; off > 0; off >>= 1)
        mx = fmaxf(mx, __shfl_xor(mx, off));
    float sum = 0.f;
    const float k = 0.0625f;                            // decoded = S*16
    #pragma unroll
    for (int j = 0; j < 64; j++) { f[j] = __expf((f[j] - mx) * k); sum += f[j]; }
    #pragma unroll
    for (int off = 32; off > 0; off >>= 1)
        sum += __shfl_xor(sum, off);
    float inv = 256.f / sum;                            // store P*256 fp8
    #pragma unroll
    for (int c = 0; c < 4; c++) {
        unsigned wv[4];
        #pragma unroll
        for (int u = 0; u < 4; u++) {
            int b = c*16 + u*4;
            int o = 0;
            o = __builtin_amdgcn_cvt_pk_fp8_f32(f[b+0]*inv, f[b+1]*inv, o, false);
            o = __builtin_amdgcn_cvt_pk_fp8_f32(f[b+2]*inv, f[b+3]*inv, o, true);
            wv[u] = (unsigned)o;
        }
        uint4 ov; ov.x = wv[0]; ov.y = wv[1]; ov.z = wv[2]; ov.w = wv[3];
        rp[c * 64 + lane] = ov;
    }
}

extern "C" void kernel_launch(void* const* d_in, const int* in_sizes, int n_in,
                              void* d_out, int out_size, void* d_ws, size_t ws_size,
                              hipStream_t stream) {
    const float* x   = (const float*)d_in[0];
    const float* gnw = (const float*)d_in[1];
    const float* gnb = (const float*)d_in[2];
    const float* wq  = (const float*)d_in[3];
    const float* bq  = (const float*)d_in[4];
    const float* wk  = (const float*)d_in[5];
    const float* bk  = (const float*)d_in[6];
    const float* wv  = (const float*)d_in[7];
    const float* bv  = (const float*)d_in[8];
    const float* wp  = (const float*)d_in[9];
    const float* bp  = (const float*)d_in[10];
    float* out = (float*)d_out;
    char*  ws  = (char*)d_ws;

    // workspace layout (~56 MB)
    float* raw = (float*)(ws + 0);                   // 2 KB  gn stat partials [64][4][2]
    float* bqk = (float*)(ws + 8192);                // 4 KB
    uchar* Wb  = (uchar*)(ws + 65536);               // 1 MB  [4][512][512] fp8 (x16)
    uchar* Hn  = (uchar*)(ws + (2ull  << 20));       // 4 MB  [2][4096][512] fp8
    uchar* QK8 = (uchar*)(ws + (8ull  << 20));       // 8 MB  [2][4096][1024] fp8 (Q|K)
    uchar* V8  = (uchar*)(ws + (16ull << 20));       // 4 MB  [2][512][4096] fp8
    uchar* Ot8 = (uchar*)(ws + (20ull << 20));       // 4 MB  [2][4096][512] fp8 (x16)
    uchar* Sb  = (uchar*)(ws + (24ull << 20));       // 32 MB [2][4096][4096] fp8 (S*16 -> P*256)

    prep_stats<<<PREP_BLOCKS + 256, 256, 0, stream>>>(wq, wk, wv, wp, bq, bk, x, Wb, bqk, raw);
    gn_apply<<<dim3(N_/64, C_/64, B_), 256, 0, stream>>>(x, raw, gnw, gnb, Hn);

    const long long sHn = (long long)N_ * C_;        // bytes (fp8)
    const long long sQK = (long long)N_ * 1024;
    const long long sV  = (long long)C_ * N_;
    const long long sS  = (long long)N_ * N_;

    // QK fused: [4096,1024] = (Hn @ [Wq;Wk]^T)/16 + bqk -> fp8   (512 blocks)
    gemm_nt8<128,1,3,512,0><<<dim3(8, 32, 2), 256, 0, stream>>>(
        Hn, C_, sHn, Wb, C_, 0, QK8, 1024, sQK, bqk, nullptr, 1.f/16.f);
    // V: [512,4096] = (Wv @ Hn^T)/16 + bv -> fp8   (512 blocks)
    gemm_nt8<64,2,3,512,0><<<dim3(32, 8, 2), 256, 0, stream>>>(
        Wb + 2*WN, C_, 0, Hn, C_, sHn, V8, N_, sV, bv, nullptr, 1.f/16.f);

    // S*16 = Q @ K^T * (scale*16) -> fp8, both batches (2048 blocks)
    const float alphaS = 0.044194173824159216f * 16.f;   // 512^-0.5 * 16
    gemm_nt8<128,0,3,512,0><<<dim3(32, 32, 2), 256, 0, stream>>>(
        QK8, 1024, sQK, QK8 + 512, 1024, sQK, Sb, N_, sS, nullptr, nullptr, alphaS);
    // softmax rows: fp8 in/out in place (2048 blocks)
    softmax_rows8<<<B_*N_/4, 256, 0, stream>>>(Sb);
    // Ot = (P8 @ V8^T) * 16/256 -> fp8 (x16)  (512 blocks, XCD-swizzled flat grid)
    gemm_nt8<64,0,3,4096,1><<<512, 256, 0, stream>>>(
        Sb, N_, sS, V8, N_, sV, Ot8, C_, sHn, nullptr, nullptr, 1.f/16.f);
    // out[b,o,n] = x + (Wp @ Ot^T)/256 + bp   (512 blocks)
    gemm_nt8<64,2,2,512,0><<<dim3(32, 8, 2), 256, 0, stream>>>(
        Wb + 3*WN, C_, 0, Ot8, C_, sHn, out, N_, (long long)C_*N_, bp, x, 1.f/256.f);
}